// Round 16
// baseline (240.649 us; speedup 1.0000x reference)
//
#include <hip/hip_runtime.h>
#include <hip/hip_bf16.h>
#include <cstdint>
#include <cstddef>

typedef __attribute__((ext_vector_type(8))) __bf16 bf16x8;
typedef __attribute__((ext_vector_type(4))) __bf16 bf16x4;
typedef __attribute__((ext_vector_type(4))) float f32x4;
typedef __attribute__((ext_vector_type(16))) float f32x16;
typedef __attribute__((ext_vector_type(4))) unsigned int uint4v;

#define MFMA16(a, b, c) __builtin_amdgcn_mfma_f32_16x16x32_bf16(a, b, c, 0, 0, 0)
#define MFMA32(a, b, c) __builtin_amdgcn_mfma_f32_32x32x16_bf16(a, b, c, 0, 0, 0)

__device__ __forceinline__ void gload_lds16(const void* g, void* l) {
  __builtin_amdgcn_global_load_lds(
      (__attribute__((address_space(1))) uint32_t*)g,
      (__attribute__((address_space(3))) uint32_t*)l,
      16, 0, 0);
}

__device__ __forceinline__ unsigned pkbf(float a, float b) {
  unsigned short x = __builtin_bit_cast(unsigned short, (__bf16)a);
  unsigned short y = __builtin_bit_cast(unsigned short, (__bf16)b);
  return (unsigned)x | ((unsigned)y << 16);
}

__device__ __forceinline__ float fexp2(float x) {
  float r;
  asm("v_exp_f32 %0, %1" : "=v"(r) : "v"(x));
  return r;
}

// ---------------- pre: qkv weight transpose (bid<3072) + LN1 (bid>=3072)
__global__ __launch_bounds__(256) void pre_kernel(
    const float* __restrict__ w_qkv, __bf16* __restrict__ wqkvT,
    const float* __restrict__ x, const float* __restrict__ ln1_w,
    const float* __restrict__ ln1_b, __bf16* __restrict__ h) {
  __shared__ float sm[32 * 33];
  int bid = blockIdx.x;
  int tx = threadIdx.x, ty = threadIdx.y;  // (32, 8)
  if (bid < 3072) {
    int bx = bid % 96, by = bid / 96;  // N=3072, K=1024
    int gcol = bx * 32 + tx;
#pragma unroll
    for (int j = 0; j < 4; j++) {
      int grow = by * 32 + ty + j * 8;
      sm[(ty + j * 8) * 33 + tx] = w_qkv[(size_t)grow * 3072 + gcol];
    }
    __syncthreads();
#pragma unroll
    for (int j = 0; j < 4; j++) {
      int n = bx * 32 + ty + j * 8;
      wqkvT[(size_t)n * 1024 + by * 32 + tx] = (__bf16)sm[tx * 33 + ty + j * 8];
    }
    return;
  }
  int row = bid - 3072;
  int t = ty * 32 + tx;
  const float4* xr = (const float4*)(x + (size_t)row * 1024);
  float4 v = xr[t];
  float s = v.x + v.y + v.z + v.w;
  float sq = v.x * v.x + v.y * v.y + v.z * v.z + v.w * v.w;
#pragma unroll
  for (int m = 1; m < 64; m <<= 1) {
    s += __shfl_xor(s, m);
    sq += __shfl_xor(sq, m);
  }
  float* rs = sm;
  float* rq = sm + 4;
  int wid = t >> 6;
  if ((t & 63) == 0) { rs[wid] = s; rq[wid] = sq; }
  __syncthreads();
  s = rs[0] + rs[1] + rs[2] + rs[3];
  sq = rq[0] + rq[1] + rq[2] + rq[3];
  float mean = s * (1.0f / 1024.0f);
  float var = sq * (1.0f / 1024.0f) - mean * mean;
  float rstd = rsqrtf(var + 1e-5f);
  float4 wv = ((const float4*)ln1_w)[t];
  float4 bv = ((const float4*)ln1_b)[t];
  bf16x4 o;
  o[0] = (__bf16)((v.x - mean) * rstd * wv.x + bv.x);
  o[1] = (__bf16)((v.y - mean) * rstd * wv.y + bv.y);
  o[2] = (__bf16)((v.z - mean) * rstd * wv.z + bv.z);
  o[3] = (__bf16)((v.w - mean) * rstd * wv.w + bv.w);
  *(bf16x4*)(h + (size_t)row * 1024 + t * 4) = o;
}

// ---------------- attn-out split-K GEMM with FUSED partial merge.
// A[m][k] = merged attn output: head h = k>>6, d = k&63:
//   A = (pO[0][h][m][d] + pO[1][h][m][d]) / (pL[0][h][m] + pL[1][h][m])
// computed in registers during A-staging (bit-identical to the old merge pass).
// M=4096, N=1024, K=1024, kchunk=512; partials P[kc][4096][1024] bf16.
__global__ __launch_bounds__(256, 2) void attnout_splitk_kernel(
    const __bf16* __restrict__ pO, const float* __restrict__ pL,
    const __bf16* __restrict__ BT, __bf16* __restrict__ P) {
  __shared__ __bf16 lsA[128 * 64];
  __shared__ __bf16 lsB[128 * 64];
  int t = threadIdx.x;
  int m0 = blockIdx.y * 128, n0 = blockIdx.x * 128;
  int kbase = blockIdx.z * 512;
  __bf16* pout = P + (size_t)blockIdx.z * 4096 * 1024;
  int wid = t >> 6, lane = t & 63, lo = lane & 15, g = lane >> 4;
  int wr = wid >> 1, wc = wid & 1;
  f32x4 acc[4][4] = {};
  int arow = t >> 3;        // 0..31
  int acol8 = (t & 7) * 8;  // col octet within 64
  const __bf16* bg = BT + (size_t)(n0 + (t >> 3)) * 1024 + (t & 7) * 8;
  for (int k0 = kbase; k0 < kbase + 512; k0 += 64) {
    int h = k0 >> 6;
#pragma unroll
    for (int i = 0; i < 4; i++)
      gload_lds16(bg + (size_t)i * 32 * 1024 + k0, &lsB[i * 2048 + t * 8]);
#pragma unroll
    for (int i = 0; i < 4; i++) {
      int row = m0 + arow + i * 32;
      size_t po = ((size_t)h * 4096 + row) * 64 + acol8;
      bf16x8 a0 = *(const bf16x8*)&pO[po];
      bf16x8 a1 = *(const bf16x8*)&pO[(size_t)16 * 4096 * 64 + po];
      float linv = 1.0f / (pL[(size_t)h * 4096 + row] +
                           pL[(size_t)16 * 4096 + (size_t)h * 4096 + row]);
      bf16x8 mg;
#pragma unroll
      for (int e = 0; e < 8; e++)
        mg[e] = (__bf16)(((float)a0[e] + (float)a1[e]) * linv);
      *(bf16x8*)&lsA[(arow + i * 32) * 64 + acol8] = mg;
    }
    __syncthreads();
#pragma unroll
    for (int kk = 0; kk < 2; kk++) {
      bf16x8 af[4], bfr[4];
#pragma unroll
      for (int mi = 0; mi < 4; mi++)
        af[mi] = *(const bf16x8*)&lsA[(wr * 64 + mi * 16 + lo) * 64 + kk * 32 + g * 8];
#pragma unroll
      for (int ni = 0; ni < 4; ni++)
        bfr[ni] = *(const bf16x8*)&lsB[(wc * 64 + ni * 16 + lo) * 64 + kk * 32 + g * 8];
#pragma unroll
      for (int mi = 0; mi < 4; mi++)
#pragma unroll
        for (int ni = 0; ni < 4; ni++)
          acc[mi][ni] = MFMA16(af[mi], bfr[ni], acc[mi][ni]);
    }
    __syncthreads();
  }
#pragma unroll
  for (int mi = 0; mi < 4; mi++) {
#pragma unroll
    for (int ni = 0; ni < 4; ni++) {
      int col = n0 + wc * 64 + ni * 16 + lo;
      int row0 = m0 + wr * 64 + mi * 16 + g * 4;
#pragma unroll
      for (int r = 0; r < 4; r++)
        pout[(size_t)(row0 + r) * 1024 + col] = (__bf16)acc[mi][ni][r];
    }
  }
}

// ---------------- fused reduce + LN2: x2 = x + p0 + p1; h = LN(x2).  One block/row.
__global__ __launch_bounds__(256) void out_reduce_ln_kernel(
    const __bf16* __restrict__ p0, const __bf16* __restrict__ p1,
    const float* __restrict__ x, const float* __restrict__ w,
    const float* __restrict__ b, float* __restrict__ x2,
    __bf16* __restrict__ h) {
  int row = blockIdx.x, t = threadIdx.x;
  size_t base = (size_t)row * 1024 + t * 4;
  bf16x4 a = *(const bf16x4*)&p0[base];
  bf16x4 b4 = *(const bf16x4*)&p1[base];
  float4 xv = *(const float4*)&x[base];
  float4 v;
  v.x = xv.x + (float)a[0] + (float)b4[0];
  v.y = xv.y + (float)a[1] + (float)b4[1];
  v.z = xv.z + (float)a[2] + (float)b4[2];
  v.w = xv.w + (float)a[3] + (float)b4[3];
  *(float4*)&x2[base] = v;
  float s = v.x + v.y + v.z + v.w;
  float sq = v.x * v.x + v.y * v.y + v.z * v.z + v.w * v.w;
#pragma unroll
  for (int m = 1; m < 64; m <<= 1) {
    s += __shfl_xor(s, m);
    sq += __shfl_xor(sq, m);
  }
  __shared__ float rs[4], rq[4];
  int wid = t >> 6;
  if ((t & 63) == 0) { rs[wid] = s; rq[wid] = sq; }
  __syncthreads();
  s = rs[0] + rs[1] + rs[2] + rs[3];
  sq = rq[0] + rq[1] + rq[2] + rq[3];
  float mean = s * (1.0f / 1024.0f);
  float var = sq * (1.0f / 1024.0f) - mean * mean;
  float rstd = rsqrtf(var + 1e-5f);
  float4 wv = ((const float4*)w)[t];
  float4 bv = ((const float4*)b)[t];
  bf16x4 o;
  o[0] = (__bf16)((v.x - mean) * rstd * wv.x + bv.x);
  o[1] = (__bf16)((v.y - mean) * rstd * wv.y + bv.y);
  o[2] = (__bf16)((v.z - mean) * rstd * wv.z + bv.z);
  o[3] = (__bf16)((v.w - mean) * rstd * wv.w + bv.w);
  *(bf16x4*)&h[base] = o;
}

// ---------------- 256^2-tile 8-phase GEMM (T2+T3+T4+T5)
// EPI 0: scatter q (PRE-SCALED by 0.125*log2e), k to [2][16][4096][64],
//        v TRANSPOSED to [16][64][4096]
// EPI 2: outb = gelu(acc + bias) bf16
// EPI 4: split-K partial -> bf16 buffer P[kchunk] (blockIdx.y = kchunk)
template <int EPI>
__global__ __launch_bounds__(512, 2) void gemm256_kernel(
    const __bf16* __restrict__ A, const __bf16* __restrict__ BT,
    int M, int N, int K, int nkc,
    const float* __restrict__ bias, __bf16* __restrict__ outb,
    __bf16* __restrict__ P0, __bf16* __restrict__ P1,
    __bf16* __restrict__ P2, __bf16* __restrict__ P3) {
  __shared__ __bf16 lsA[2][2][128 * 64];
  __shared__ __bf16 lsB[2][2][128 * 64];
  int nbx = N >> 8;
  int nwg = (M >> 8) * nbx;
  int bid = blockIdx.x;
  int swz = (bid & 7) * (nwg >> 3) + (bid >> 3);
  int m0 = (swz / nbx) << 8, n0 = (swz % nbx) << 8;
  int kc = blockIdx.y;
  int kt0 = kc * nkc;
  int t = threadIdx.x;
  int wid = t >> 6, lane = t & 63, lo = lane & 15, g = lane >> 4;
  int wm = wid >> 2, wn = wid & 3;
  int srow = t >> 3, sgrp = t & 7;

  auto stA = [&](int d, int h, int kt) {
#pragma unroll
    for (int i = 0; i < 2; i++) {
      int row = i * 64 + srow;
      int gs = (sgrp ^ (row & 7)) * 8;
      gload_lds16(A + (size_t)(m0 + h * 128 + row) * K + kt * 64 + gs,
                  &lsA[d][h][(i * 512 + t) * 8]);
    }
  };
  auto stB = [&](int d, int h, int kt) {
#pragma unroll
    for (int i = 0; i < 2; i++) {
      int row = i * 64 + srow;
      int gs = (sgrp ^ (row & 7)) * 8;
      gload_lds16(BT + (size_t)(n0 + h * 128 + row) * K + kt * 64 + gs,
                  &lsB[d][h][(i * 512 + t) * 8]);
    }
  };
  auto rdA = [&](int d, int f, int kk) -> bf16x8 {
    int row = (f & 3) * 32 + wm * 16 + lo;
    return *(const bf16x8*)&lsA[d][f >> 2][row * 64 + (((kk * 4 + g) ^ (lo & 7)) * 8)];
  };
  auto rdB = [&](int d, int ni, int kk) -> bf16x8 {
    int row = (ni & 1) * 64 + wn * 16 + lo;
    return *(const bf16x8*)&lsB[d][ni >> 1][row * 64 + (((kk * 4 + g) ^ (lo & 7)) * 8)];
  };

  f32x4 acc[8][4] = {};
  stA(0, 0, kt0); stB(0, 0, kt0); stB(0, 1, kt0); stA(0, 1, kt0);
  asm volatile("s_waitcnt vmcnt(4)" ::: "memory");
  __builtin_amdgcn_s_barrier();

  for (int ki = 0; ki < nkc; ki++) {
    int kt = kt0 + ki;
    int d = ki & 1, nx = d ^ 1;
    bool pf = (ki + 1) < nkc;
    bf16x8 fa[4][2], fb0[2][2], fb1[2][2];
#pragma unroll
    for (int f = 0; f < 4; f++) { fa[f][0] = rdA(d, f, 0); fa[f][1] = rdA(d, f, 1); }
#pragma unroll
    for (int n = 0; n < 2; n++) { fb0[n][0] = rdB(d, n, 0); fb0[n][1] = rdB(d, n, 1); }
    if (pf) { stA(nx, 0, kt + 1); stB(nx, 0, kt + 1); }
    __builtin_amdgcn_s_barrier();
    __builtin_amdgcn_s_setprio(1);
#pragma unroll
    for (int f = 0; f < 4; f++)
#pragma unroll
      for (int n = 0; n < 2; n++) {
        acc[f][n] = MFMA16(fa[f][0], fb0[n][0], acc[f][n]);
        acc[f][n] = MFMA16(fa[f][1], fb0[n][1], acc[f][n]);
      }
    __builtin_amdgcn_s_setprio(0);
    asm volatile("s_waitcnt vmcnt(6)" ::: "memory");
    __builtin_amdgcn_s_barrier();
#pragma unroll
    for (int n = 0; n < 2; n++) { fb1[n][0] = rdB(d, 2 + n, 0); fb1[n][1] = rdB(d, 2 + n, 1); }
    if (pf) stB(nx, 1, kt + 1);
    __builtin_amdgcn_s_barrier();
    __builtin_amdgcn_s_setprio(1);
#pragma unroll
    for (int f = 0; f < 4; f++)
#pragma unroll
      for (int n = 0; n < 2; n++) {
        acc[f][2 + n] = MFMA16(fa[f][0], fb1[n][0], acc[f][2 + n]);
        acc[f][2 + n] = MFMA16(fa[f][1], fb1[n][1], acc[f][2 + n]);
      }
    __builtin_amdgcn_s_setprio(0);
    asm volatile("s_waitcnt vmcnt(6)" ::: "memory");
    __builtin_amdgcn_s_barrier();
#pragma unroll
    for (int f = 0; f < 4; f++) { fa[f][0] = rdA(d, 4 + f, 0); fa[f][1] = rdA(d, 4 + f, 1); }
    if (pf) stA(nx, 1, kt + 1);
    __builtin_amdgcn_s_barrier();
    __builtin_amdgcn_s_setprio(1);
#pragma unroll
    for (int f = 0; f < 4; f++)
#pragma unroll
      for (int n = 0; n < 2; n++) {
        acc[4 + f][2 + n] = MFMA16(fa[f][0], fb1[n][0], acc[4 + f][2 + n]);
        acc[4 + f][2 + n] = MFMA16(fa[f][1], fb1[n][1], acc[4 + f][2 + n]);
      }
    __builtin_amdgcn_s_setprio(0);
    __builtin_amdgcn_s_barrier();
    __builtin_amdgcn_s_setprio(1);
#pragma unroll
    for (int f = 0; f < 4; f++)
#pragma unroll
      for (int n = 0; n < 2; n++) {
        acc[4 + f][n] = MFMA16(fa[f][0], fb0[n][0], acc[4 + f][n]);
        acc[4 + f][n] = MFMA16(fa[f][1], fb0[n][1], acc[4 + f][n]);
      }
    __builtin_amdgcn_s_setprio(0);
    asm volatile("s_waitcnt vmcnt(4)" ::: "memory");
    __builtin_amdgcn_s_barrier();
  }

  __bf16* pk = (EPI == 4) ? ((kc == 0) ? P0 : (kc == 1) ? P1 : (kc == 2) ? P2 : P3)
                          : nullptr;
#pragma unroll
  for (int f = 0; f < 8; f++) {
    int row0 = m0 + (f >> 2) * 128 + (f & 3) * 32 + wm * 16 + g * 4;
#pragma unroll
    for (int ni = 0; ni < 4; ni++) {
      int col = n0 + (ni >> 1) * 128 + (ni & 1) * 64 + wn * 16 + lo;
      if (EPI == 0) {
        int sE = col >> 10, rem = col & 1023, hh = rem >> 6, dd = rem & 63;
        if (sE < 2) {
          float qs = (sE == 0) ? 0.1803368801111204f : 1.0f;  // 0.125*log2(e)
#pragma unroll
          for (int r = 0; r < 4; r++)
            outb[((size_t)(sE * 16 + hh) * 4096 + row0 + r) * 64 + dd] =
                (__bf16)(acc[f][ni][r] * qs);
        } else {
          bf16x4 pk4;
#pragma unroll
          for (int r = 0; r < 4; r++) pk4[r] = (__bf16)acc[f][ni][r];
          *(bf16x4*)&outb[(size_t)32 * 4096 * 64 + ((size_t)(hh * 64 + dd)) * 4096 + row0] = pk4;
        }
      } else if (EPI == 2) {
        float bv = bias[col];
#pragma unroll
        for (int r = 0; r < 4; r++) {
          float vv = acc[f][ni][r] + bv;
          float gg = 0.5f * vv * (1.0f + erff(vv * 0.70710678118f));
          outb[(size_t)(row0 + r) * N + col] = (__bf16)gg;
        }
      } else {
#pragma unroll
        for (int r = 0; r < 4; r++)
          pk[(size_t)(row0 + r) * N + col] = (__bf16)acc[f][ni][r];
      }
    }
  }
}

// ---------------- split-K reduce: out = x2 + p0+p1+p2+p3 + bias  (4096x1024)
__global__ __launch_bounds__(256) void ff2_reduce_kernel(
    const __bf16* __restrict__ p0, const __bf16* __restrict__ p1,
    const __bf16* __restrict__ p2, const __bf16* __restrict__ p3,
    const float* __restrict__ x2, const float* __restrict__ bias,
    float* __restrict__ out) {
  size_t i8 = ((size_t)blockIdx.x * 256 + threadIdx.x) * 8;
  bf16x8 a = *(const bf16x8*)&p0[i8];
  bf16x8 b = *(const bf16x8*)&p1[i8];
  bf16x8 c = *(const bf16x8*)&p2[i8];
  bf16x8 d = *(const bf16x8*)&p3[i8];
  int col = (int)(i8 & 1023);
  float4 xa = *(const float4*)&x2[i8];
  float4 xb = *(const float4*)&x2[i8 + 4];
  float4 ba = *(const float4*)&bias[col];
  float4 bb = *(const float4*)&bias[col + 4];
  float4 oa, ob;
  oa.x = xa.x + ba.x + (float)a[0] + (float)b[0] + (float)c[0] + (float)d[0];
  oa.y = xa.y + ba.y + (float)a[1] + (float)b[1] + (float)c[1] + (float)d[1];
  oa.z = xa.z + ba.z + (float)a[2] + (float)b[2] + (float)c[2] + (float)d[2];
  oa.w = xa.w + ba.w + (float)a[3] + (float)b[3] + (float)c[3] + (float)d[3];
  ob.x = xb.x + bb.x + (float)a[4] + (float)b[4] + (float)c[4] + (float)d[4];
  ob.y = xb.y + bb.y + (float)a[5] + (float)b[5] + (float)c[5] + (float)d[5];
  ob.z = xb.z + bb.z + (float)a[6] + (float)b[6] + (float)c[6] + (float)d[6];
  ob.w = xb.w + bb.w + (float)a[7] + (float)b[7] + (float)c[7] + (float)d[7];
  *(float4*)&out[i8] = oa;
  *(float4*)&out[i8 + 4] = ob;
}

// ---------------- causal flash attention (bid < 1024) + piggybacked weight
// transposes for w_o/w_ff1/w_ff2 (bid >= 1024, backfill attn's tail).
// Block = 256 thr = 4 waves (qsub 0-3); grid dim = (head, it, kpar).
// Writes unnormalized bf16 partial + l; merged inside attnout_splitk_kernel.
__global__ __launch_bounds__(256, 4) void attn_fused_kernel(
    const __bf16* __restrict__ Q, const __bf16* __restrict__ Kb,
    const __bf16* __restrict__ VTb, __bf16* __restrict__ pO,
    float* __restrict__ pL,
    const float* __restrict__ w_o, __bf16* __restrict__ woT,
    const float* __restrict__ w_ff1, __bf16* __restrict__ wff1T,
    const float* __restrict__ w_ff2, __bf16* __restrict__ wff2T) {
  constexpr int NSEQ = 4096;
  __shared__ __bf16 lds[2][2][64 * 64];  // attn: [dbl][K/VT] 32 KiB; transpose: tile
  int orig = blockIdx.x;
  int t = threadIdx.x;

  if (orig >= 1024) {
    // ---- transpose body: in [K][N] f32 -> out [N][K] bf16, 256 threads
    int b = orig - 1024;
    const float* in; __bf16* outw; int K, N, bx, by;
    if (b < 1024)      { in = w_o;   outw = woT;   K = 1024; N = 1024; bx = b & 31;  by = b >> 5; }
    else if (b < 5120) { int c = b - 1024; in = w_ff1; outw = wff1T; K = 1024; N = 4096; bx = c & 127; by = c >> 7; }
    else               { int c = b - 5120; in = w_ff2; outw = wff2T; K = 4096; N = 1024; bx = c & 31;  by = c >> 5; }
    float* tile = (float*)lds;  // [32][33]
    int tx = t & 31, ty = t >> 5;  // ty 0..7
#pragma unroll
    for (int j = 0; j < 4; j++) {
      int r = ty + j * 8;
      tile[r * 33 + tx] = in[(size_t)(by * 32 + r) * N + bx * 32 + tx];
    }
    __syncthreads();
#pragma unroll
    for (int j = 0; j < 4; j++) {
      int r = ty + j * 8;
      outw[(size_t)(bx * 32 + r) * K + by * 32 + tx] = (__bf16)tile[tx * 33 + r];
    }
    return;
  }

  int xcd = orig & 7, r = orig >> 3;     // r 0..127
  int kpar = r & 1;
  int r2 = r >> 1;                       // 0..63
  int hv = r2 >> 5;
  int hd2 = (r2 >> 4) & 1;
  int itr = r2 & 15;
  int head = xcd * 2 + hd2;
  int it = hv ? itr : (31 - itr);        // heavy first, light backfills
  int wid = t >> 6, lane = t & 63;
  int lo = lane & 31, hi = lane >> 5;
  int qsub = wid;
  const __bf16* kh = Kb + (size_t)head * NSEQ * 64;
  const __bf16* vth = VTb + (size_t)head * 64 * NSEQ;
  int qlow = it * 128 + qsub * 32;
  int qrow = qlow + lo;
  int qtop = qlow + 31;
  const __bf16* qh = Q + (size_t)head * NSEQ * 64 + (size_t)qrow * 64;
  bf16x8 bq[4];
#pragma unroll
  for (int c = 0; c < 4; c++) bq[c] = *(const bf16x8*)(qh + c * 16 + hi * 8);

  const unsigned onesu = 0x3F803F80u;  // 2 x bf16 1.0
  uint4v onev = {onesu, onesu, onesu, onesu};
  bf16x8 vones = __builtin_bit_cast(bf16x8, onev);

  f32x16 acc0 = {}, acc1 = {};
  f32x16 lacc = {};              // row-sum accumulator via ones-MFMA
  int srow = t >> 3;             // 0..31
  int sgs = ((t & 7) ^ (srow & 7)) * 8;

  int off[4];
#pragma unroll
  for (int c = 0; c < 4; c++) off[c] = lo * 64 + (((c * 2 + hi) ^ (lo & 7)) * 8);
  const __bf16* lk0 = &lds[0][0][0];
  const __bf16* lk1 = &lds[1][0][0];
  const __bf16* lv0 = &lds[0][1][0];
  const __bf16* lv1 = &lds[1][1][0];
  const __bf16* khs = kh + srow * 64 + sgs;
  const __bf16* vts = vth + (size_t)srow * NSEQ + sgs;

  // stage K-tile kt rows [i*32,i*32+32) + V-tile kt (2 issues each)
  auto stage_tile = [&](int d, int kt) {
#pragma unroll
    for (int i = 0; i < 2; i++) {
      gload_lds16(khs + (size_t)kt * 4096 + i * 2048, &lds[d][0][i * 2048 + t * 8]);
      gload_lds16(vts + (size_t)i * 32 * NSEQ + kt * 64, &lds[d][1][i * 2048 + t * 8]);
    }
  };

  int ns = it + 1;  // this parity has tiles kt = 2s+kpar, s = 0..it
  stage_tile(0, kpar);
  __syncthreads();

#define ATTN_STEP(CUR)                                                         \
  {                                                                            \
    int kt = 2 * j + kpar;                                                     \
    if (j + 1 < ns) stage_tile((CUR) ^ 1, kt + 2);                             \
    if (kt * 64 <= qtop) {                                                     \
      const __bf16* lk = (CUR) ? lk1 : lk0;                                    \
      const __bf16* lvt = (CUR) ? lv1 : lv0;                                   \
      f32x16 s0 = {}, s1 = {};                                                 \
      __builtin_amdgcn_s_setprio(1);                                           \
      _Pragma("unroll") for (int c = 0; c < 4; c++) {                          \
        bf16x8 ka0 = *(const bf16x8*)&lk[off[c]];                              \
        bf16x8 ka1 = *(const bf16x8*)&lk[2048 + off[c]];                       \
        s0 = MFMA32(ka0, bq[c], s0);                                           \
        s1 = MFMA32(ka1, bq[c], s1);                                           \
      }                                                                        \
      __builtin_amdgcn_s_setprio(0);                                           \
      if (kt * 64 + 63 > qlow) {                                               \
        _Pragma("unroll") for (int i = 0; i < 16; i++) {                       \
          int key0 = kt * 64 + (i & 3) + 8 * (i >> 2) + 4 * hi;                \
          if (key0 > qrow) s0[i] = -3.0e38f;                                   \
          if (key0 + 32 > qrow) s1[i] = -3.0e38f;                              \
        }                                                                      \
      }                                                                        \
      _Pragma("unroll") for (int i = 0; i < 16; i++) {                         \
        s0[i] = fexp2(s0[i]);                                                  \
        s1[i] = fexp2(s1[i]);                                                  \
      }                                                                        \
      uint4v pw[4];                                                            \
      _Pragma("unroll") for (int b = 0; b < 2; b++) {                          \
        int off2 = b * 8;                                                      \
        unsigned a0 = pkbf(s0[off2 + 0], s0[off2 + 1]);                        \
        unsigned a1 = pkbf(s0[off2 + 2], s0[off2 + 3]);                        \
        unsigned b0 = pkbf(s0[off2 + 4], s0[off2 + 5]);                        \
        unsigned b1 = pkbf(s0[off2 + 6], s0[off2 + 7]);                        \
        asm("v_permlane32_swap_b32 %0, %1" : "+v"(a0), "+v"(b0));              \
        asm("v_permlane32_swap_b32 %0, %1" : "+v"(a1), "+v"(b1));              \
        pw[b][0] = a0; pw[b][1] = a1; pw[b][2] = b0; pw[b][3] = b1;            \
        unsigned c0 = pkbf(s1[off2 + 0], s1[off2 + 1]);                        \
        unsigned c1 = pkbf(s1[off2 + 2], s1[off2 + 3]);                        \
        unsigned d0 = pkbf(s1[off2 + 4], s1[off2 + 5]);                        \
        unsigned d1 = pkbf(s1[off2 + 6], s1[off2 + 7]);                        \
        asm("v_permlane32_swap_b32 %0, %1" : "+v"(c0), "+v"(d0));              \
        asm("v_permlane32_swap_b32 %0, %1" : "+v"(c1), "+v"(d1));              \
        pw[2 + b][0] = c0; pw[2 + b][1] = c1; pw[2 + b][2] = d0;               \
        pw[2 + b][3] = d1;                                                     \
      }                                                                        \
      __builtin_amdgcn_s_setprio(1);                                           \
      _Pragma("unroll") for (int b = 0; b < 4; b++) {                          \
        bf16x8 pf = __builtin_bit_cast(bf16x8, pw[b]);                         \
        bf16x8 va0 = *(const bf16x8*)&lvt[off[b]];                             \
        bf16x8 va1 = *(const bf16x8*)&lvt[2048 + off[b]];                      \
        acc0 = MFMA32(va0, pf, acc0);                                          \
        acc1 = MFMA32(va1, pf, acc1);                                          \
        lacc = MFMA32(vones, pf, lacc);                                        \
      }                                                                        \
      __builtin_amdgcn_s_setprio(0);                                           \
    }                                                                          \
    __syncthreads();                                                           \
  }

  int j = 0;
  for (;;) {
    ATTN_STEP(0);
    if (++j >= ns) break;
    ATTN_STEP(1);
    if (++j >= ns) break;
  }
#undef ATTN_STEP

  // ---- epilogue: write unnormalized bf16 partial (swizzled bounce) + l
  if (hi == 0) pL[((size_t)kpar * 16 + head) * 4096 + qlow + lo] = lacc[0];
  __bf16* bounce = (__bf16*)lds;
  __bf16* region = bounce + qsub * 2048;  // 32 rows x 64 cols, per-wave private
#pragma unroll
  for (int dt = 0; dt < 2; dt++) {
#pragma unroll
    for (int rp = 0; rp < 8; rp++) {
      int rr = rp * 2;
      float e0 = dt ? acc1[rr] : acc0[rr];
      float e1 = dt ? acc1[rr + 1] : acc0[rr + 1];
      int d = dt * 32 + (rr & 3) + 8 * (rr >> 2) + 4 * hi;
      int bytecol = d * 2;
      int g16 = bytecol >> 4, rem16 = bytecol & 15;
      *(unsigned*)((char*)region + lo * 128 + ((g16 ^ (lo & 7)) * 16 + rem16)) = pkbf(e0, e1);
    }
  }
  __syncthreads();
  __bf16* pok = pO + (size_t)kpar * 16 * 4096 * 64 + (((size_t)head * 4096) + qlow) * 64;
#pragma unroll
  for (int j2 = 0; j2 < 4; j2++) {
    int idx = j2 * 64 + lane;
    int row = idx >> 3, g = idx & 7;
    bf16x8 v = *(const bf16x8*)((char*)region + row * 128 + ((g ^ (row & 7)) * 16));
    *(bf16x8*)&pok[(size_t)row * 64 + g * 8] = v;
  }
}

extern "C" void kernel_launch(void* const* d_in, const int* in_sizes, int n_in,
                              void* d_out, int out_size, void* d_ws, size_t ws_size,
                              hipStream_t stream) {
  const float* x = (const float*)d_in[0];
  const float* ln1_w = (const float*)d_in[1];
  const float* ln1_b = (const float*)d_in[2];
  const float* ln2_w = (const float*)d_in[3];
  const float* ln2_b = (const float*)d_in[4];
  const float* w_qkv = (const float*)d_in[5];  // [1024][3072]
  const float* w_o = (const float*)d_in[6];    // [1024][1024]
  const float* w_ff1 = (const float*)d_in[7];  // [1024][4096]
  const float* b_ff1 = (const float*)d_in[8];
  const float* w_ff2 = (const float*)d_in[9];  // [4096][1024]
  const float* b_ff2 = (const float*)d_in[10];
  float* out = (float*)d_out;

  const size_t D = 1024, NT = 4096;
  __bf16* wqkvT = (__bf16*)d_ws;                 // [0,6) MB
  __bf16* woT = wqkvT + 3072 * D;                // [6,8)
  __bf16* wff1T = woT + D * D;                   // [8,16)
  __bf16* wff2T = wff1T + 4096 * D;              // [16,24)
  __bf16* hbuf = wff2T + D * 4096;               // [24,32)
  __bf16* qkvb = hbuf + NT * D;                  // [32,56)
  __bf16* attnb = qkvb + 3 * NT * D;             // [56,64) (unused now)
  __bf16* a1 = qkvb;                             // [32,64) overlaps dead qkv
  float* x2 = (float*)(attnb + NT * D);          // [64,80) f32
  __bf16* p0 = (__bf16*)d_ws;                    // [0,8)  (wqkvT/woT dead by ff2)
  __bf16* p1 = p0 + NT * D;                      // [8,16) (wff1T dead after ff1)
  __bf16* p2 = hbuf;                             // [24,32) (h2 dead after ff1)
  __bf16* p3 = (__bf16*)(x2 + NT * D);           // [80,88)
  __bf16* pA = qkvb;                             // [32,40) dead q after attn-out
  __bf16* pB = pA + NT * D;                      // [40,48) dead k after attn-out
  // attn partials: pO [2][16][4096][64] bf16 over the x2 region (x2 written later);
  // pL [2][16][4096] f32 at [80,80.5) (overwritten later by ff2's p3)
  __bf16* pOb = (__bf16*)x2;                     // [64,80)
  float* pLb = (float*)p3;                       // [80,80.5)

  dim3 tb(32, 8);
  pre_kernel<<<3072 + 4096, tb, 0, stream>>>(w_qkv, wqkvT, x, ln1_w, ln1_b, hbuf);
  gemm256_kernel<0><<<192, 512, 0, stream>>>(hbuf, wqkvT, 4096, 3072, 1024, 16,
                                             nullptr, qkvb, nullptr, nullptr, nullptr, nullptr);
  // attention (1024 blocks, kpar-split) + piggybacked wo/ff1/ff2 transposes
  attn_fused_kernel<<<1024 + 9216, 256, 0, stream>>>(
      qkvb, qkvb + 16 * NT * 64, qkvb + 32 * NT * 64, pOb, pLb,
      w_o, woT, w_ff1, wff1T, w_ff2, wff2T);
  // attn-out split-K GEMM with fused partial merge (A staged from pO/pL)
  attnout_splitk_kernel<<<dim3(8, 32, 2), 256, 0, stream>>>(pOb, pLb, woT, pA);
  out_reduce_ln_kernel<<<4096, 256, 0, stream>>>(pA, pB, x, ln2_w, ln2_b, x2, hbuf);
  gemm256_kernel<2><<<256, 512, 0, stream>>>(hbuf, wff1T, 4096, 4096, 1024, 16,
                                             b_ff1, a1, nullptr, nullptr, nullptr, nullptr);
  gemm256_kernel<4><<<dim3(64, 4), 512, 0, stream>>>(a1, wff2T, 4096, 1024, 4096, 16,
                                                     nullptr, nullptr, p0, p1, p2, p3);
  ff2_reduce_kernel<<<2048, 256, 0, stream>>>(p0, p1, p2, p3, x2, b_ff2, out);
}

// Round 17
// 233.511 us; speedup vs baseline: 1.0306x; 1.0306x over previous
//
#include <hip/hip_runtime.h>
#include <hip/hip_bf16.h>
#include <cstdint>
#include <cstddef>

typedef __attribute__((ext_vector_type(8))) __bf16 bf16x8;
typedef __attribute__((ext_vector_type(4))) __bf16 bf16x4;
typedef __attribute__((ext_vector_type(4))) float f32x4;
typedef __attribute__((ext_vector_type(16))) float f32x16;
typedef __attribute__((ext_vector_type(4))) unsigned int uint4v;

#define MFMA16(a, b, c) __builtin_amdgcn_mfma_f32_16x16x32_bf16(a, b, c, 0, 0, 0)
#define MFMA32(a, b, c) __builtin_amdgcn_mfma_f32_32x32x16_bf16(a, b, c, 0, 0, 0)

__device__ __forceinline__ void gload_lds16(const void* g, void* l) {
  __builtin_amdgcn_global_load_lds(
      (__attribute__((address_space(1))) uint32_t*)g,
      (__attribute__((address_space(3))) uint32_t*)l,
      16, 0, 0);
}

__device__ __forceinline__ unsigned pkbf(float a, float b) {
  unsigned short x = __builtin_bit_cast(unsigned short, (__bf16)a);
  unsigned short y = __builtin_bit_cast(unsigned short, (__bf16)b);
  return (unsigned)x | ((unsigned)y << 16);
}

__device__ __forceinline__ float fexp2(float x) {
  float r;
  asm("v_exp_f32 %0, %1" : "=v"(r) : "v"(x));
  return r;
}

// ---------------- pre: qkv weight transpose (bid<3072) + LN1 (bid>=3072)
__global__ __launch_bounds__(256) void pre_kernel(
    const float* __restrict__ w_qkv, __bf16* __restrict__ wqkvT,
    const float* __restrict__ x, const float* __restrict__ ln1_w,
    const float* __restrict__ ln1_b, __bf16* __restrict__ h) {
  __shared__ float sm[32 * 33];
  int bid = blockIdx.x;
  int tx = threadIdx.x, ty = threadIdx.y;  // (32, 8)
  if (bid < 3072) {
    int bx = bid % 96, by = bid / 96;  // N=3072, K=1024
    int gcol = bx * 32 + tx;
#pragma unroll
    for (int j = 0; j < 4; j++) {
      int grow = by * 32 + ty + j * 8;
      sm[(ty + j * 8) * 33 + tx] = w_qkv[(size_t)grow * 3072 + gcol];
    }
    __syncthreads();
#pragma unroll
    for (int j = 0; j < 4; j++) {
      int n = bx * 32 + ty + j * 8;
      wqkvT[(size_t)n * 1024 + by * 32 + tx] = (__bf16)sm[tx * 33 + ty + j * 8];
    }
    return;
  }
  int row = bid - 3072;
  int t = ty * 32 + tx;
  const float4* xr = (const float4*)(x + (size_t)row * 1024);
  float4 v = xr[t];
  float s = v.x + v.y + v.z + v.w;
  float sq = v.x * v.x + v.y * v.y + v.z * v.z + v.w * v.w;
#pragma unroll
  for (int m = 1; m < 64; m <<= 1) {
    s += __shfl_xor(s, m);
    sq += __shfl_xor(sq, m);
  }
  float* rs = sm;
  float* rq = sm + 4;
  int wid = t >> 6;
  if ((t & 63) == 0) { rs[wid] = s; rq[wid] = sq; }
  __syncthreads();
  s = rs[0] + rs[1] + rs[2] + rs[3];
  sq = rq[0] + rq[1] + rq[2] + rq[3];
  float mean = s * (1.0f / 1024.0f);
  float var = sq * (1.0f / 1024.0f) - mean * mean;
  float rstd = rsqrtf(var + 1e-5f);
  float4 wv = ((const float4*)ln1_w)[t];
  float4 bv = ((const float4*)ln1_b)[t];
  bf16x4 o;
  o[0] = (__bf16)((v.x - mean) * rstd * wv.x + bv.x);
  o[1] = (__bf16)((v.y - mean) * rstd * wv.y + bv.y);
  o[2] = (__bf16)((v.z - mean) * rstd * wv.z + bv.z);
  o[3] = (__bf16)((v.w - mean) * rstd * wv.w + bv.w);
  *(bf16x4*)(h + (size_t)row * 1024 + t * 4) = o;
}

// ---------------- 128^2-tile split-K GEMM (m97 structure): bf16 partials
__global__ __launch_bounds__(256, 2) void gemm_splitk128_kernel(
    const __bf16* __restrict__ A, const __bf16* __restrict__ BT,
    int M, int N, int K, int kchunk, __bf16* __restrict__ P) {
  __shared__ __bf16 lsA[128 * 64];
  __shared__ __bf16 lsB[128 * 64];
  int t = threadIdx.x;
  int m0 = blockIdx.y * 128, n0 = blockIdx.x * 128;
  int kbase = blockIdx.z * kchunk;
  __bf16* pout = P + (size_t)blockIdx.z * M * N;
  int wid = t >> 6, lane = t & 63, lo = lane & 15, g = lane >> 4;
  int wr = wid >> 1, wc = wid & 1;
  f32x4 acc[4][4] = {};
  const __bf16* ag = A + (size_t)(m0 + (t >> 3)) * K + (t & 7) * 8;
  const __bf16* bg = BT + (size_t)(n0 + (t >> 3)) * K + (t & 7) * 8;
  for (int k0 = kbase; k0 < kbase + kchunk; k0 += 64) {
#pragma unroll
    for (int i = 0; i < 4; i++) {
      gload_lds16(ag + (size_t)i * 32 * K + k0, &lsA[i * 2048 + t * 8]);
      gload_lds16(bg + (size_t)i * 32 * K + k0, &lsB[i * 2048 + t * 8]);
    }
    __syncthreads();
#pragma unroll
    for (int kk = 0; kk < 2; kk++) {
      bf16x8 af[4], bfr[4];
#pragma unroll
      for (int mi = 0; mi < 4; mi++)
        af[mi] = *(const bf16x8*)&lsA[(wr * 64 + mi * 16 + lo) * 64 + kk * 32 + g * 8];
#pragma unroll
      for (int ni = 0; ni < 4; ni++)
        bfr[ni] = *(const bf16x8*)&lsB[(wc * 64 + ni * 16 + lo) * 64 + kk * 32 + g * 8];
#pragma unroll
      for (int mi = 0; mi < 4; mi++)
#pragma unroll
        for (int ni = 0; ni < 4; ni++)
          acc[mi][ni] = MFMA16(af[mi], bfr[ni], acc[mi][ni]);
    }
    __syncthreads();
  }
#pragma unroll
  for (int mi = 0; mi < 4; mi++) {
#pragma unroll
    for (int ni = 0; ni < 4; ni++) {
      int col = n0 + wc * 64 + ni * 16 + lo;
      int row0 = m0 + wr * 64 + mi * 16 + g * 4;
#pragma unroll
      for (int r = 0; r < 4; r++)
        pout[(size_t)(row0 + r) * N + col] = (__bf16)acc[mi][ni][r];
    }
  }
}

// ---------------- fused reduce + LN2: x2 = x + p0 + p1; h = LN(x2).  One block/row.
__global__ __launch_bounds__(256) void out_reduce_ln_kernel(
    const __bf16* __restrict__ p0, const __bf16* __restrict__ p1,
    const float* __restrict__ x, const float* __restrict__ w,
    const float* __restrict__ b, float* __restrict__ x2,
    __bf16* __restrict__ h) {
  int row = blockIdx.x, t = threadIdx.x;
  size_t base = (size_t)row * 1024 + t * 4;
  bf16x4 a = *(const bf16x4*)&p0[base];
  bf16x4 b4 = *(const bf16x4*)&p1[base];
  float4 xv = *(const float4*)&x[base];
  float4 v;
  v.x = xv.x + (float)a[0] + (float)b4[0];
  v.y = xv.y + (float)a[1] + (float)b4[1];
  v.z = xv.z + (float)a[2] + (float)b4[2];
  v.w = xv.w + (float)a[3] + (float)b4[3];
  *(float4*)&x2[base] = v;
  float s = v.x + v.y + v.z + v.w;
  float sq = v.x * v.x + v.y * v.y + v.z * v.z + v.w * v.w;
#pragma unroll
  for (int m = 1; m < 64; m <<= 1) {
    s += __shfl_xor(s, m);
    sq += __shfl_xor(sq, m);
  }
  __shared__ float rs[4], rq[4];
  int wid = t >> 6;
  if ((t & 63) == 0) { rs[wid] = s; rq[wid] = sq; }
  __syncthreads();
  s = rs[0] + rs[1] + rs[2] + rs[3];
  sq = rq[0] + rq[1] + rq[2] + rq[3];
  float mean = s * (1.0f / 1024.0f);
  float var = sq * (1.0f / 1024.0f) - mean * mean;
  float rstd = rsqrtf(var + 1e-5f);
  float4 wv = ((const float4*)w)[t];
  float4 bv = ((const float4*)b)[t];
  bf16x4 o;
  o[0] = (__bf16)((v.x - mean) * rstd * wv.x + bv.x);
  o[1] = (__bf16)((v.y - mean) * rstd * wv.y + bv.y);
  o[2] = (__bf16)((v.z - mean) * rstd * wv.z + bv.z);
  o[3] = (__bf16)((v.w - mean) * rstd * wv.w + bv.w);
  *(bf16x4*)&h[base] = o;
}

// ---------------- 256^2-tile 8-phase GEMM (T2+T3+T4+T5)
// EPI 0: scatter q (PRE-SCALED by 0.125*log2e), k to [2][16][4096][64],
//        v TRANSPOSED to [16][64][4096]
// EPI 2: outb = gelu(acc + bias) bf16
// EPI 4: split-K partial -> bf16 buffer P[kchunk] (blockIdx.y = kchunk)
template <int EPI>
__global__ __launch_bounds__(512, 2) void gemm256_kernel(
    const __bf16* __restrict__ A, const __bf16* __restrict__ BT,
    int M, int N, int K, int nkc,
    const float* __restrict__ bias, __bf16* __restrict__ outb,
    __bf16* __restrict__ P0, __bf16* __restrict__ P1,
    __bf16* __restrict__ P2, __bf16* __restrict__ P3) {
  __shared__ __bf16 lsA[2][2][128 * 64];
  __shared__ __bf16 lsB[2][2][128 * 64];
  int nbx = N >> 8;
  int nwg = (M >> 8) * nbx;
  int bid = blockIdx.x;
  int swz = (bid & 7) * (nwg >> 3) + (bid >> 3);
  int m0 = (swz / nbx) << 8, n0 = (swz % nbx) << 8;
  int kc = blockIdx.y;
  int kt0 = kc * nkc;
  int t = threadIdx.x;
  int wid = t >> 6, lane = t & 63, lo = lane & 15, g = lane >> 4;
  int wm = wid >> 2, wn = wid & 3;
  int srow = t >> 3, sgrp = t & 7;

  auto stA = [&](int d, int h, int kt) {
#pragma unroll
    for (int i = 0; i < 2; i++) {
      int row = i * 64 + srow;
      int gs = (sgrp ^ (row & 7)) * 8;
      gload_lds16(A + (size_t)(m0 + h * 128 + row) * K + kt * 64 + gs,
                  &lsA[d][h][(i * 512 + t) * 8]);
    }
  };
  auto stB = [&](int d, int h, int kt) {
#pragma unroll
    for (int i = 0; i < 2; i++) {
      int row = i * 64 + srow;
      int gs = (sgrp ^ (row & 7)) * 8;
      gload_lds16(BT + (size_t)(n0 + h * 128 + row) * K + kt * 64 + gs,
                  &lsB[d][h][(i * 512 + t) * 8]);
    }
  };
  auto rdA = [&](int d, int f, int kk) -> bf16x8 {
    int row = (f & 3) * 32 + wm * 16 + lo;
    return *(const bf16x8*)&lsA[d][f >> 2][row * 64 + (((kk * 4 + g) ^ (lo & 7)) * 8)];
  };
  auto rdB = [&](int d, int ni, int kk) -> bf16x8 {
    int row = (ni & 1) * 64 + wn * 16 + lo;
    return *(const bf16x8*)&lsB[d][ni >> 1][row * 64 + (((kk * 4 + g) ^ (lo & 7)) * 8)];
  };

  f32x4 acc[8][4] = {};
  stA(0, 0, kt0); stB(0, 0, kt0); stB(0, 1, kt0); stA(0, 1, kt0);
  asm volatile("s_waitcnt vmcnt(4)" ::: "memory");
  __builtin_amdgcn_s_barrier();

  for (int ki = 0; ki < nkc; ki++) {
    int kt = kt0 + ki;
    int d = ki & 1, nx = d ^ 1;
    bool pf = (ki + 1) < nkc;
    bf16x8 fa[4][2], fb0[2][2], fb1[2][2];
#pragma unroll
    for (int f = 0; f < 4; f++) { fa[f][0] = rdA(d, f, 0); fa[f][1] = rdA(d, f, 1); }
#pragma unroll
    for (int n = 0; n < 2; n++) { fb0[n][0] = rdB(d, n, 0); fb0[n][1] = rdB(d, n, 1); }
    if (pf) { stA(nx, 0, kt + 1); stB(nx, 0, kt + 1); }
    __builtin_amdgcn_s_barrier();
    __builtin_amdgcn_s_setprio(1);
#pragma unroll
    for (int f = 0; f < 4; f++)
#pragma unroll
      for (int n = 0; n < 2; n++) {
        acc[f][n] = MFMA16(fa[f][0], fb0[n][0], acc[f][n]);
        acc[f][n] = MFMA16(fa[f][1], fb0[n][1], acc[f][n]);
      }
    __builtin_amdgcn_s_setprio(0);
    asm volatile("s_waitcnt vmcnt(6)" ::: "memory");
    __builtin_amdgcn_s_barrier();
#pragma unroll
    for (int n = 0; n < 2; n++) { fb1[n][0] = rdB(d, 2 + n, 0); fb1[n][1] = rdB(d, 2 + n, 1); }
    if (pf) stB(nx, 1, kt + 1);
    __builtin_amdgcn_s_barrier();
    __builtin_amdgcn_s_setprio(1);
#pragma unroll
    for (int f = 0; f < 4; f++)
#pragma unroll
      for (int n = 0; n < 2; n++) {
        acc[f][2 + n] = MFMA16(fa[f][0], fb1[n][0], acc[f][2 + n]);
        acc[f][2 + n] = MFMA16(fa[f][1], fb1[n][1], acc[f][2 + n]);
      }
    __builtin_amdgcn_s_setprio(0);
    asm volatile("s_waitcnt vmcnt(6)" ::: "memory");
    __builtin_amdgcn_s_barrier();
#pragma unroll
    for (int f = 0; f < 4; f++) { fa[f][0] = rdA(d, 4 + f, 0); fa[f][1] = rdA(d, 4 + f, 1); }
    if (pf) stA(nx, 1, kt + 1);
    __builtin_amdgcn_s_barrier();
    __builtin_amdgcn_s_setprio(1);
#pragma unroll
    for (int f = 0; f < 4; f++)
#pragma unroll
      for (int n = 0; n < 2; n++) {
        acc[4 + f][2 + n] = MFMA16(fa[f][0], fb1[n][0], acc[4 + f][2 + n]);
        acc[4 + f][2 + n] = MFMA16(fa[f][1], fb1[n][1], acc[4 + f][2 + n]);
      }
    __builtin_amdgcn_s_setprio(0);
    __builtin_amdgcn_s_barrier();
    __builtin_amdgcn_s_setprio(1);
#pragma unroll
    for (int f = 0; f < 4; f++)
#pragma unroll
      for (int n = 0; n < 2; n++) {
        acc[4 + f][n] = MFMA16(fa[f][0], fb0[n][0], acc[4 + f][n]);
        acc[4 + f][n] = MFMA16(fa[f][1], fb0[n][1], acc[4 + f][n]);
      }
    __builtin_amdgcn_s_setprio(0);
    asm volatile("s_waitcnt vmcnt(4)" ::: "memory");
    __builtin_amdgcn_s_barrier();
  }

  __bf16* pk = (EPI == 4) ? ((kc == 0) ? P0 : (kc == 1) ? P1 : (kc == 2) ? P2 : P3)
                          : nullptr;
#pragma unroll
  for (int f = 0; f < 8; f++) {
    int row0 = m0 + (f >> 2) * 128 + (f & 3) * 32 + wm * 16 + g * 4;
#pragma unroll
    for (int ni = 0; ni < 4; ni++) {
      int col = n0 + (ni >> 1) * 128 + (ni & 1) * 64 + wn * 16 + lo;
      if (EPI == 0) {
        int sE = col >> 10, rem = col & 1023, hh = rem >> 6, dd = rem & 63;
        if (sE < 2) {
          float qs = (sE == 0) ? 0.1803368801111204f : 1.0f;  // 0.125*log2(e)
#pragma unroll
          for (int r = 0; r < 4; r++)
            outb[((size_t)(sE * 16 + hh) * 4096 + row0 + r) * 64 + dd] =
                (__bf16)(acc[f][ni][r] * qs);
        } else {
          bf16x4 pk4;
#pragma unroll
          for (int r = 0; r < 4; r++) pk4[r] = (__bf16)acc[f][ni][r];
          *(bf16x4*)&outb[(size_t)32 * 4096 * 64 + ((size_t)(hh * 64 + dd)) * 4096 + row0] = pk4;
        }
      } else if (EPI == 2) {
        float bv = bias[col];
#pragma unroll
        for (int r = 0; r < 4; r++) {
          float vv = acc[f][ni][r] + bv;
          float gg = 0.5f * vv * (1.0f + erff(vv * 0.70710678118f));
          outb[(size_t)(row0 + r) * N + col] = (__bf16)gg;
        }
      } else {
#pragma unroll
        for (int r = 0; r < 4; r++)
          pk[(size_t)(row0 + r) * N + col] = (__bf16)acc[f][ni][r];
      }
    }
  }
}

// ---------------- split-K reduce: out = x2 + p0+p1+p2+p3 + bias  (4096x1024)
__global__ __launch_bounds__(256) void ff2_reduce_kernel(
    const __bf16* __restrict__ p0, const __bf16* __restrict__ p1,
    const __bf16* __restrict__ p2, const __bf16* __restrict__ p3,
    const float* __restrict__ x2, const float* __restrict__ bias,
    float* __restrict__ out) {
  size_t i8 = ((size_t)blockIdx.x * 256 + threadIdx.x) * 8;
  bf16x8 a = *(const bf16x8*)&p0[i8];
  bf16x8 b = *(const bf16x8*)&p1[i8];
  bf16x8 c = *(const bf16x8*)&p2[i8];
  bf16x8 d = *(const bf16x8*)&p3[i8];
  int col = (int)(i8 & 1023);
  float4 xa = *(const float4*)&x2[i8];
  float4 xb = *(const float4*)&x2[i8 + 4];
  float4 ba = *(const float4*)&bias[col];
  float4 bb = *(const float4*)&bias[col + 4];
  float4 oa, ob;
  oa.x = xa.x + ba.x + (float)a[0] + (float)b[0] + (float)c[0] + (float)d[0];
  oa.y = xa.y + ba.y + (float)a[1] + (float)b[1] + (float)c[1] + (float)d[1];
  oa.z = xa.z + ba.z + (float)a[2] + (float)b[2] + (float)c[2] + (float)d[2];
  oa.w = xa.w + ba.w + (float)a[3] + (float)b[3] + (float)c[3] + (float)d[3];
  ob.x = xb.x + bb.x + (float)a[4] + (float)b[4] + (float)c[4] + (float)d[4];
  ob.y = xb.y + bb.y + (float)a[5] + (float)b[5] + (float)c[5] + (float)d[5];
  ob.z = xb.z + bb.z + (float)a[6] + (float)b[6] + (float)c[6] + (float)d[6];
  ob.w = xb.w + bb.w + (float)a[7] + (float)b[7] + (float)c[7] + (float)d[7];
  *(float4*)&out[i8] = oa;
  *(float4*)&out[i8 + 4] = ob;
}

// ---------------- causal flash attention (bid < 512) + piggybacked weight
// transposes (bid >= 512). Block = 256 thr = 4 waves (qsub 0-3), FULL k-range
// per block (no kpar split, no merge) with 32 KiB double-buffered LDS ->
// 4 independent blocks/CU, all 512 blocks co-resident. Direct normalized
// output. Q pre-scaled by 0.125*log2e, static-max softmax, l via ones-MFMA.
__global__ __launch_bounds__(256, 4) void attn_fused_kernel(
    const __bf16* __restrict__ Q, const __bf16* __restrict__ Kb,
    const __bf16* __restrict__ VTb, __bf16* __restrict__ O,
    const float* __restrict__ w_o, __bf16* __restrict__ woT,
    const float* __restrict__ w_ff1, __bf16* __restrict__ wff1T,
    const float* __restrict__ w_ff2, __bf16* __restrict__ wff2T) {
  constexpr int NSEQ = 4096;
  __shared__ __bf16 lds[2][2][64 * 64];  // [dbl][K/VT], 32 KiB
  int orig = blockIdx.x;
  int t = threadIdx.x;

  if (orig >= 512) {
    // ---- transpose body: in [K][N] f32 -> out [N][K] bf16, 256 threads
    int b = orig - 512;
    const float* in; __bf16* outw; int K, N, bx, by;
    if (b < 1024)      { in = w_o;   outw = woT;   K = 1024; N = 1024; bx = b & 31;  by = b >> 5; }
    else if (b < 5120) { int c = b - 1024; in = w_ff1; outw = wff1T; K = 1024; N = 4096; bx = c & 127; by = c >> 7; }
    else               { int c = b - 5120; in = w_ff2; outw = wff2T; K = 4096; N = 1024; bx = c & 31;  by = c >> 5; }
    float* tile = (float*)lds;  // [32][33]
    int tx = t & 31, ty = t >> 5;  // ty 0..7
#pragma unroll
    for (int j = 0; j < 4; j++) {
      int r = ty + j * 8;
      tile[r * 33 + tx] = in[(size_t)(by * 32 + r) * N + bx * 32 + tx];
    }
    __syncthreads();
#pragma unroll
    for (int j = 0; j < 4; j++) {
      int r = ty + j * 8;
      outw[(size_t)(bx * 32 + r) * K + by * 32 + tx] = (__bf16)tile[tx * 33 + r];
    }
    return;
  }

  int xcd = orig & 7, r2 = orig >> 3;    // r2 0..63
  int hv = r2 >> 5;
  int hd2 = (r2 >> 4) & 1;
  int itr = r2 & 15;
  int head = xcd * 2 + hd2;
  int it = hv ? itr : (31 - itr);        // heavy first, light backfills
  int wid = t >> 6, lane = t & 63;
  int lo = lane & 31, hi = lane >> 5;
  int qsub = wid;
  const __bf16* kh = Kb + (size_t)head * NSEQ * 64;
  const __bf16* vth = VTb + (size_t)head * 64 * NSEQ;
  int qlow = it * 128 + qsub * 32;
  int qrow = qlow + lo;
  int qtop = qlow + 31;
  const __bf16* qh = Q + (size_t)head * NSEQ * 64 + (size_t)qrow * 64;
  bf16x8 bq[4];
#pragma unroll
  for (int c = 0; c < 4; c++) bq[c] = *(const bf16x8*)(qh + c * 16 + hi * 8);

  const unsigned onesu = 0x3F803F80u;  // 2 x bf16 1.0
  uint4v onev = {onesu, onesu, onesu, onesu};
  bf16x8 vones = __builtin_bit_cast(bf16x8, onev);

  f32x16 acc0 = {}, acc1 = {};
  f32x16 lacc = {};              // row-sum accumulator via ones-MFMA
  int srow = t >> 3;             // 0..31
  int sgs = ((t & 7) ^ (srow & 7)) * 8;

  int off[4];
#pragma unroll
  for (int c = 0; c < 4; c++) off[c] = lo * 64 + (((c * 2 + hi) ^ (lo & 7)) * 8);
  const __bf16* lk0 = &lds[0][0][0];
  const __bf16* lk1 = &lds[1][0][0];
  const __bf16* lv0 = &lds[0][1][0];
  const __bf16* lv1 = &lds[1][1][0];
  const __bf16* khs = kh + srow * 64 + sgs;
  const __bf16* vts = vth + (size_t)srow * NSEQ + sgs;

  // stage K-tile kt rows [i*32,i*32+32) + V-tile kt (2 issues each)
  auto stage_tile = [&](int d, int kt) {
#pragma unroll
    for (int i = 0; i < 2; i++) {
      gload_lds16(khs + (size_t)kt * 4096 + i * 2048, &lds[d][0][i * 2048 + t * 8]);
      gload_lds16(vts + (size_t)i * 32 * NSEQ + kt * 64, &lds[d][1][i * 2048 + t * 8]);
    }
  };

  int nt = 2 * it + 2;  // all k-tiles for this q-tile
  stage_tile(0, 0);
  __syncthreads();

#define ATTN_STEP(CUR)                                                         \
  {                                                                            \
    if (j + 1 < nt) stage_tile((CUR) ^ 1, j + 1);                              \
    if (j * 64 <= qtop) {                                                      \
      int kt = j;                                                              \
      const __bf16* lk = (CUR) ? lk1 : lk0;                                    \
      const __bf16* lvt = (CUR) ? lv1 : lv0;                                   \
      f32x16 s0 = {}, s1 = {};                                                 \
      __builtin_amdgcn_s_setprio(1);                                           \
      _Pragma("unroll") for (int c = 0; c < 4; c++) {                          \
        bf16x8 ka0 = *(const bf16x8*)&lk[off[c]];                              \
        bf16x8 ka1 = *(const bf16x8*)&lk[2048 + off[c]];                       \
        s0 = MFMA32(ka0, bq[c], s0);                                           \
        s1 = MFMA32(ka1, bq[c], s1);                                           \
      }                                                                        \
      __builtin_amdgcn_s_setprio(0);                                           \
      if (kt * 64 + 63 > qlow) {                                               \
        _Pragma("unroll") for (int i = 0; i < 16; i++) {                       \
          int key0 = kt * 64 + (i & 3) + 8 * (i >> 2) + 4 * hi;                \
          if (key0 > qrow) s0[i] = -3.0e38f;                                   \
          if (key0 + 32 > qrow) s1[i] = -3.0e38f;                              \
        }                                                                      \
      }                                                                        \
      _Pragma("unroll") for (int i = 0; i < 16; i++) {                         \
        s0[i] = fexp2(s0[i]);                                                  \
        s1[i] = fexp2(s1[i]);                                                  \
      }                                                                        \
      uint4v pw[4];                                                            \
      _Pragma("unroll") for (int b = 0; b < 2; b++) {                          \
        int off2 = b * 8;                                                      \
        unsigned a0 = pkbf(s0[off2 + 0], s0[off2 + 1]);                        \
        unsigned a1 = pkbf(s0[off2 + 2], s0[off2 + 3]);                        \
        unsigned b0 = pkbf(s0[off2 + 4], s0[off2 + 5]);                        \
        unsigned b1 = pkbf(s0[off2 + 6], s0[off2 + 7]);                        \
        asm("v_permlane32_swap_b32 %0, %1" : "+v"(a0), "+v"(b0));              \
        asm("v_permlane32_swap_b32 %0, %1" : "+v"(a1), "+v"(b1));              \
        pw[b][0] = a0; pw[b][1] = a1; pw[b][2] = b0; pw[b][3] = b1;            \
        unsigned c0 = pkbf(s1[off2 + 0], s1[off2 + 1]);                        \
        unsigned c1 = pkbf(s1[off2 + 2], s1[off2 + 3]);                        \
        unsigned d0 = pkbf(s1[off2 + 4], s1[off2 + 5]);                        \
        unsigned d1 = pkbf(s1[off2 + 6], s1[off2 + 7]);                        \
        asm("v_permlane32_swap_b32 %0, %1" : "+v"(c0), "+v"(d0));              \
        asm("v_permlane32_swap_b32 %0, %1" : "+v"(c1), "+v"(d1));              \
        pw[2 + b][0] = c0; pw[2 + b][1] = c1; pw[2 + b][2] = d0;               \
        pw[2 + b][3] = d1;                                                     \
      }                                                                        \
      __builtin_amdgcn_s_setprio(1);                                           \
      _Pragma("unroll") for (int b = 0; b < 4; b++) {                          \
        bf16x8 pf = __builtin_bit_cast(bf16x8, pw[b]);                         \
        bf16x8 va0 = *(const bf16x8*)&lvt[off[b]];                             \
        bf16x8 va1 = *(const bf16x8*)&lvt[2048 + off[b]];                      \
        acc0 = MFMA32(va0, pf, acc0);                                          \
        acc1 = MFMA32(va1, pf, acc1);                                          \
        lacc = MFMA32(vones, pf, lacc);                                        \
      }                                                                        \
      __builtin_amdgcn_s_setprio(0);                                           \
    }                                                                          \
    __syncthreads();                                                           \
  }

  int j = 0;
  for (;;) {
    ATTN_STEP(0);
    if (++j >= nt) break;
    ATTN_STEP(1);
    if (++j >= nt) break;
  }
#undef ATTN_STEP

  // ---- epilogue: normalize directly (l complete), bounce via LDS, store
  float linv = 1.0f / lacc[0];
  __bf16* bounce = (__bf16*)lds;
  __bf16* region = bounce + qsub * 2048;  // 32 rows x 64 cols, per-wave private
#pragma unroll
  for (int dt = 0; dt < 2; dt++) {
#pragma unroll
    for (int rp = 0; rp < 8; rp++) {
      int rr = rp * 2;
      float e0 = (dt ? acc1[rr] : acc0[rr]) * linv;
      float e1 = (dt ? acc1[rr + 1] : acc0[rr + 1]) * linv;
      int d = dt * 32 + (rr & 3) + 8 * (rr >> 2) + 4 * hi;
      int bytecol = d * 2;
      int g16 = bytecol >> 4, rem16 = bytecol & 15;
      *(unsigned*)((char*)region + lo * 128 + ((g16 ^ (lo & 7)) * 16 + rem16)) = pkbf(e0, e1);
    }
  }
  __syncthreads();
#pragma unroll
  for (int j2 = 0; j2 < 4; j2++) {
    int idx = j2 * 64 + lane;
    int row = idx >> 3, g = idx & 7;
    bf16x8 v = *(const bf16x8*)((char*)region + row * 128 + ((g ^ (row & 7)) * 16));
    *(bf16x8*)&O[(size_t)(it * 128 + qsub * 32 + row) * 1024 + head * 64 + g * 8] = v;
  }
}

extern "C" void kernel_launch(void* const* d_in, const int* in_sizes, int n_in,
                              void* d_out, int out_size, void* d_ws, size_t ws_size,
                              hipStream_t stream) {
  const float* x = (const float*)d_in[0];
  const float* ln1_w = (const float*)d_in[1];
  const float* ln1_b = (const float*)d_in[2];
  const float* ln2_w = (const float*)d_in[3];
  const float* ln2_b = (const float*)d_in[4];
  const float* w_qkv = (const float*)d_in[5];  // [1024][3072]
  const float* w_o = (const float*)d_in[6];    // [1024][1024]
  const float* w_ff1 = (const float*)d_in[7];  // [1024][4096]
  const float* b_ff1 = (const float*)d_in[8];
  const float* w_ff2 = (const float*)d_in[9];  // [4096][1024]
  const float* b_ff2 = (const float*)d_in[10];
  float* out = (float*)d_out;

  const size_t D = 1024, NT = 4096;
  __bf16* wqkvT = (__bf16*)d_ws;                 // [0,6) MB
  __bf16* woT = wqkvT + 3072 * D;                // [6,8)
  __bf16* wff1T = woT + D * D;                   // [8,16)
  __bf16* wff2T = wff1T + 4096 * D;              // [16,24)
  __bf16* hbuf = wff2T + D * 4096;               // [24,32)
  __bf16* qkvb = hbuf + NT * D;                  // [32,56)
  __bf16* attnb = qkvb + 3 * NT * D;             // [56,64)
  __bf16* a1 = qkvb;                             // [32,64) overlaps dead qkv
  float* x2 = (float*)(attnb + NT * D);          // [64,80) f32
  __bf16* p0 = (__bf16*)d_ws;                    // [0,8)  (wqkvT/woT dead by ff2)
  __bf16* p1 = p0 + NT * D;                      // [8,16) (wff1T dead after ff1)
  __bf16* p2 = hbuf;                             // [24,32) (h2 dead after ff1)
  __bf16* p3 = (__bf16*)(x2 + NT * D);           // [80,88)
  __bf16* pA = qkvb;                             // [32,40) dead q after attn-out
  __bf16* pB = pA + NT * D;                      // [40,48) dead k after attn-out

  dim3 tb(32, 8);
  pre_kernel<<<3072 + 4096, tb, 0, stream>>>(w_qkv, wqkvT, x, ln1_w, ln1_b, hbuf);
  gemm256_kernel<0><<<192, 512, 0, stream>>>(hbuf, wqkvT, 4096, 3072, 1024, 16,
                                             nullptr, qkvb, nullptr, nullptr, nullptr, nullptr);
  // attention (512 blocks, full k-range, direct output) + piggybacked transposes
  attn_fused_kernel<<<512 + 9216, 256, 0, stream>>>(
      qkvb, qkvb + 16 * NT * 64, qkvb + 32 * NT * 64, attnb,
      w_o, woT, w_ff1, wff1T, w_ff2, wff2T);
  gemm_splitk128_kernel<<<dim3(8, 32, 2), 256, 0, stream>>>(
      attnb, woT, 4096, 1024, 1024, 512, pA);
  out_reduce_ln_kernel<<<4096, 256, 0, stream>>>(pA, pB, x, ln2_w, ln2_b, x2, hbuf);
  gemm256_kernel<2><<<256, 512, 0, stream>>>(hbuf, wff1T, 4096, 4096, 1024, 16,
                                             b_ff1, a1, nullptr, nullptr, nullptr, nullptr);
  gemm256_kernel<4><<<dim3(64, 4), 512, 0, stream>>>(a1, wff2T, 4096, 1024, 4096, 16,
                                                     nullptr, nullptr, p0, p1, p2, p3);
  ff2_reduce_kernel<<<2048, 256, 0, stream>>>(p0, p1, p2, p3, x2, b_ff2, out);
}

// Round 18
// 232.136 us; speedup vs baseline: 1.0367x; 1.0059x over previous
//
#include <hip/hip_runtime.h>
#include <hip/hip_bf16.h>
#include <cstdint>
#include <cstddef>

typedef __attribute__((ext_vector_type(8))) __bf16 bf16x8;
typedef __attribute__((ext_vector_type(4))) __bf16 bf16x4;
typedef __attribute__((ext_vector_type(4))) float f32x4;
typedef __attribute__((ext_vector_type(16))) float f32x16;
typedef __attribute__((ext_vector_type(4))) unsigned int uint4v;

#define MFMA16(a, b, c) __builtin_amdgcn_mfma_f32_16x16x32_bf16(a, b, c, 0, 0, 0)
#define MFMA32(a, b, c) __builtin_amdgcn_mfma_f32_32x32x16_bf16(a, b, c, 0, 0, 0)

__device__ __forceinline__ void gload_lds16(const void* g, void* l) {
  __builtin_amdgcn_global_load_lds(
      (__attribute__((address_space(1))) uint32_t*)g,
      (__attribute__((address_space(3))) uint32_t*)l,
      16, 0, 0);
}

__device__ __forceinline__ unsigned pkbf(float a, float b) {
  unsigned short x = __builtin_bit_cast(unsigned short, (__bf16)a);
  unsigned short y = __builtin_bit_cast(unsigned short, (__bf16)b);
  return (unsigned)x | ((unsigned)y << 16);
}

__device__ __forceinline__ float fexp2(float x) {
  float r;
  asm("v_exp_f32 %0, %1" : "=v"(r) : "v"(x));
  return r;
}

// ---------------- pre: qkv weight transpose (bid<3072) + LN1 (bid>=3072)
__global__ __launch_bounds__(256) void pre_kernel(
    const float* __restrict__ w_qkv, __bf16* __restrict__ wqkvT,
    const float* __restrict__ x, const float* __restrict__ ln1_w,
    const float* __restrict__ ln1_b, __bf16* __restrict__ h) {
  __shared__ float sm[32 * 33];
  int bid = blockIdx.x;
  int tx = threadIdx.x, ty = threadIdx.y;  // (32, 8)
  if (bid < 3072) {
    int bx = bid % 96, by = bid / 96;  // N=3072, K=1024
    int gcol = bx * 32 + tx;
#pragma unroll
    for (int j = 0; j < 4; j++) {
      int grow = by * 32 + ty + j * 8;
      sm[(ty + j * 8) * 33 + tx] = w_qkv[(size_t)grow * 3072 + gcol];
    }
    __syncthreads();
#pragma unroll
    for (int j = 0; j < 4; j++) {
      int n = bx * 32 + ty + j * 8;
      wqkvT[(size_t)n * 1024 + by * 32 + tx] = (__bf16)sm[tx * 33 + ty + j * 8];
    }
    return;
  }
  int row = bid - 3072;
  int t = ty * 32 + tx;
  const float4* xr = (const float4*)(x + (size_t)row * 1024);
  float4 v = xr[t];
  float s = v.x + v.y + v.z + v.w;
  float sq = v.x * v.x + v.y * v.y + v.z * v.z + v.w * v.w;
#pragma unroll
  for (int m = 1; m < 64; m <<= 1) {
    s += __shfl_xor(s, m);
    sq += __shfl_xor(sq, m);
  }
  float* rs = sm;
  float* rq = sm + 4;
  int wid = t >> 6;
  if ((t & 63) == 0) { rs[wid] = s; rq[wid] = sq; }
  __syncthreads();
  s = rs[0] + rs[1] + rs[2] + rs[3];
  sq = rq[0] + rq[1] + rq[2] + rq[3];
  float mean = s * (1.0f / 1024.0f);
  float var = sq * (1.0f / 1024.0f) - mean * mean;
  float rstd = rsqrtf(var + 1e-5f);
  float4 wv = ((const float4*)ln1_w)[t];
  float4 bv = ((const float4*)ln1_b)[t];
  bf16x4 o;
  o[0] = (__bf16)((v.x - mean) * rstd * wv.x + bv.x);
  o[1] = (__bf16)((v.y - mean) * rstd * wv.y + bv.y);
  o[2] = (__bf16)((v.z - mean) * rstd * wv.z + bv.z);
  o[3] = (__bf16)((v.w - mean) * rstd * wv.w + bv.w);
  *(bf16x4*)(h + (size_t)row * 1024 + t * 4) = o;
}

// ---------------- 128^2-tile split-K GEMM (m97 structure): bf16 partials
__global__ __launch_bounds__(256, 2) void gemm_splitk128_kernel(
    const __bf16* __restrict__ A, const __bf16* __restrict__ BT,
    int M, int N, int K, int kchunk, __bf16* __restrict__ P) {
  __shared__ __bf16 lsA[128 * 64];
  __shared__ __bf16 lsB[128 * 64];
  int t = threadIdx.x;
  int m0 = blockIdx.y * 128, n0 = blockIdx.x * 128;
  int kbase = blockIdx.z * kchunk;
  __bf16* pout = P + (size_t)blockIdx.z * M * N;
  int wid = t >> 6, lane = t & 63, lo = lane & 15, g = lane >> 4;
  int wr = wid >> 1, wc = wid & 1;
  f32x4 acc[4][4] = {};
  const __bf16* ag = A + (size_t)(m0 + (t >> 3)) * K + (t & 7) * 8;
  const __bf16* bg = BT + (size_t)(n0 + (t >> 3)) * K + (t & 7) * 8;
  for (int k0 = kbase; k0 < kbase + kchunk; k0 += 64) {
#pragma unroll
    for (int i = 0; i < 4; i++) {
      gload_lds16(ag + (size_t)i * 32 * K + k0, &lsA[i * 2048 + t * 8]);
      gload_lds16(bg + (size_t)i * 32 * K + k0, &lsB[i * 2048 + t * 8]);
    }
    __syncthreads();
#pragma unroll
    for (int kk = 0; kk < 2; kk++) {
      bf16x8 af[4], bfr[4];
#pragma unroll
      for (int mi = 0; mi < 4; mi++)
        af[mi] = *(const bf16x8*)&lsA[(wr * 64 + mi * 16 + lo) * 64 + kk * 32 + g * 8];
#pragma unroll
      for (int ni = 0; ni < 4; ni++)
        bfr[ni] = *(const bf16x8*)&lsB[(wc * 64 + ni * 16 + lo) * 64 + kk * 32 + g * 8];
#pragma unroll
      for (int mi = 0; mi < 4; mi++)
#pragma unroll
        for (int ni = 0; ni < 4; ni++)
          acc[mi][ni] = MFMA16(af[mi], bfr[ni], acc[mi][ni]);
    }
    __syncthreads();
  }
#pragma unroll
  for (int mi = 0; mi < 4; mi++) {
#pragma unroll
    for (int ni = 0; ni < 4; ni++) {
      int col = n0 + wc * 64 + ni * 16 + lo;
      int row0 = m0 + wr * 64 + mi * 16 + g * 4;
#pragma unroll
      for (int r = 0; r < 4; r++)
        pout[(size_t)(row0 + r) * N + col] = (__bf16)acc[mi][ni][r];
    }
  }
}

// ---------------- fused reduce + LN2: x2 = x + p0 + p1; h = LN(x2).  One block/row.
__global__ __launch_bounds__(256) void out_reduce_ln_kernel(
    const __bf16* __restrict__ p0, const __bf16* __restrict__ p1,
    const float* __restrict__ x, const float* __restrict__ w,
    const float* __restrict__ b, float* __restrict__ x2,
    __bf16* __restrict__ h) {
  int row = blockIdx.x, t = threadIdx.x;
  size_t base = (size_t)row * 1024 + t * 4;
  bf16x4 a = *(const bf16x4*)&p0[base];
  bf16x4 b4 = *(const bf16x4*)&p1[base];
  float4 xv = *(const float4*)&x[base];
  float4 v;
  v.x = xv.x + (float)a[0] + (float)b4[0];
  v.y = xv.y + (float)a[1] + (float)b4[1];
  v.z = xv.z + (float)a[2] + (float)b4[2];
  v.w = xv.w + (float)a[3] + (float)b4[3];
  *(float4*)&x2[base] = v;
  float s = v.x + v.y + v.z + v.w;
  float sq = v.x * v.x + v.y * v.y + v.z * v.z + v.w * v.w;
#pragma unroll
  for (int m = 1; m < 64; m <<= 1) {
    s += __shfl_xor(s, m);
    sq += __shfl_xor(sq, m);
  }
  __shared__ float rs[4], rq[4];
  int wid = t >> 6;
  if ((t & 63) == 0) { rs[wid] = s; rq[wid] = sq; }
  __syncthreads();
  s = rs[0] + rs[1] + rs[2] + rs[3];
  sq = rq[0] + rq[1] + rq[2] + rq[3];
  float mean = s * (1.0f / 1024.0f);
  float var = sq * (1.0f / 1024.0f) - mean * mean;
  float rstd = rsqrtf(var + 1e-5f);
  float4 wv = ((const float4*)w)[t];
  float4 bv = ((const float4*)b)[t];
  bf16x4 o;
  o[0] = (__bf16)((v.x - mean) * rstd * wv.x + bv.x);
  o[1] = (__bf16)((v.y - mean) * rstd * wv.y + bv.y);
  o[2] = (__bf16)((v.z - mean) * rstd * wv.z + bv.z);
  o[3] = (__bf16)((v.w - mean) * rstd * wv.w + bv.w);
  *(bf16x4*)&h[base] = o;
}

// ---------------- 256^2-tile 8-phase GEMM (T2+T3+T4+T5)
// EPI 0: scatter q (PRE-SCALED by 0.125*log2e), k to [2][16][4096][64],
//        v TRANSPOSED to [16][64][4096]
// EPI 2: outb = gelu(acc + bias) bf16
// EPI 4: split-K partial -> bf16 buffer P[kchunk] (blockIdx.y = kchunk)
template <int EPI>
__global__ __launch_bounds__(512, 2) void gemm256_kernel(
    const __bf16* __restrict__ A, const __bf16* __restrict__ BT,
    int M, int N, int K, int nkc,
    const float* __restrict__ bias, __bf16* __restrict__ outb,
    __bf16* __restrict__ P0, __bf16* __restrict__ P1,
    __bf16* __restrict__ P2, __bf16* __restrict__ P3) {
  __shared__ __bf16 lsA[2][2][128 * 64];
  __shared__ __bf16 lsB[2][2][128 * 64];
  int nbx = N >> 8;
  int nwg = (M >> 8) * nbx;
  int bid = blockIdx.x;
  int swz = (bid & 7) * (nwg >> 3) + (bid >> 3);
  int m0 = (swz / nbx) << 8, n0 = (swz % nbx) << 8;
  int kc = blockIdx.y;
  int kt0 = kc * nkc;
  int t = threadIdx.x;
  int wid = t >> 6, lane = t & 63, lo = lane & 15, g = lane >> 4;
  int wm = wid >> 2, wn = wid & 3;
  int srow = t >> 3, sgrp = t & 7;

  auto stA = [&](int d, int h, int kt) {
#pragma unroll
    for (int i = 0; i < 2; i++) {
      int row = i * 64 + srow;
      int gs = (sgrp ^ (row & 7)) * 8;
      gload_lds16(A + (size_t)(m0 + h * 128 + row) * K + kt * 64 + gs,
                  &lsA[d][h][(i * 512 + t) * 8]);
    }
  };
  auto stB = [&](int d, int h, int kt) {
#pragma unroll
    for (int i = 0; i < 2; i++) {
      int row = i * 64 + srow;
      int gs = (sgrp ^ (row & 7)) * 8;
      gload_lds16(BT + (size_t)(n0 + h * 128 + row) * K + kt * 64 + gs,
                  &lsB[d][h][(i * 512 + t) * 8]);
    }
  };
  auto rdA = [&](int d, int f, int kk) -> bf16x8 {
    int row = (f & 3) * 32 + wm * 16 + lo;
    return *(const bf16x8*)&lsA[d][f >> 2][row * 64 + (((kk * 4 + g) ^ (lo & 7)) * 8)];
  };
  auto rdB = [&](int d, int ni, int kk) -> bf16x8 {
    int row = (ni & 1) * 64 + wn * 16 + lo;
    return *(const bf16x8*)&lsB[d][ni >> 1][row * 64 + (((kk * 4 + g) ^ (lo & 7)) * 8)];
  };

  f32x4 acc[8][4] = {};
  stA(0, 0, kt0); stB(0, 0, kt0); stB(0, 1, kt0); stA(0, 1, kt0);
  asm volatile("s_waitcnt vmcnt(4)" ::: "memory");
  __builtin_amdgcn_s_barrier();

  for (int ki = 0; ki < nkc; ki++) {
    int kt = kt0 + ki;
    int d = ki & 1, nx = d ^ 1;
    bool pf = (ki + 1) < nkc;
    bf16x8 fa[4][2], fb0[2][2], fb1[2][2];
#pragma unroll
    for (int f = 0; f < 4; f++) { fa[f][0] = rdA(d, f, 0); fa[f][1] = rdA(d, f, 1); }
#pragma unroll
    for (int n = 0; n < 2; n++) { fb0[n][0] = rdB(d, n, 0); fb0[n][1] = rdB(d, n, 1); }
    if (pf) { stA(nx, 0, kt + 1); stB(nx, 0, kt + 1); }
    __builtin_amdgcn_s_barrier();
    __builtin_amdgcn_s_setprio(1);
#pragma unroll
    for (int f = 0; f < 4; f++)
#pragma unroll
      for (int n = 0; n < 2; n++) {
        acc[f][n] = MFMA16(fa[f][0], fb0[n][0], acc[f][n]);
        acc[f][n] = MFMA16(fa[f][1], fb0[n][1], acc[f][n]);
      }
    __builtin_amdgcn_s_setprio(0);
    asm volatile("s_waitcnt vmcnt(6)" ::: "memory");
    __builtin_amdgcn_s_barrier();
#pragma unroll
    for (int n = 0; n < 2; n++) { fb1[n][0] = rdB(d, 2 + n, 0); fb1[n][1] = rdB(d, 2 + n, 1); }
    if (pf) stB(nx, 1, kt + 1);
    __builtin_amdgcn_s_barrier();
    __builtin_amdgcn_s_setprio(1);
#pragma unroll
    for (int f = 0; f < 4; f++)
#pragma unroll
      for (int n = 0; n < 2; n++) {
        acc[f][2 + n] = MFMA16(fa[f][0], fb1[n][0], acc[f][2 + n]);
        acc[f][2 + n] = MFMA16(fa[f][1], fb1[n][1], acc[f][2 + n]);
      }
    __builtin_amdgcn_s_setprio(0);
    asm volatile("s_waitcnt vmcnt(6)" ::: "memory");
    __builtin_amdgcn_s_barrier();
#pragma unroll
    for (int f = 0; f < 4; f++) { fa[f][0] = rdA(d, 4 + f, 0); fa[f][1] = rdA(d, 4 + f, 1); }
    if (pf) stA(nx, 1, kt + 1);
    __builtin_amdgcn_s_barrier();
    __builtin_amdgcn_s_setprio(1);
#pragma unroll
    for (int f = 0; f < 4; f++)
#pragma unroll
      for (int n = 0; n < 2; n++) {
        acc[4 + f][2 + n] = MFMA16(fa[f][0], fb1[n][0], acc[4 + f][2 + n]);
        acc[4 + f][2 + n] = MFMA16(fa[f][1], fb1[n][1], acc[4 + f][2 + n]);
      }
    __builtin_amdgcn_s_setprio(0);
    __builtin_amdgcn_s_barrier();
    __builtin_amdgcn_s_setprio(1);
#pragma unroll
    for (int f = 0; f < 4; f++)
#pragma unroll
      for (int n = 0; n < 2; n++) {
        acc[4 + f][n] = MFMA16(fa[f][0], fb0[n][0], acc[4 + f][n]);
        acc[4 + f][n] = MFMA16(fa[f][1], fb0[n][1], acc[4 + f][n]);
      }
    __builtin_amdgcn_s_setprio(0);
    asm volatile("s_waitcnt vmcnt(4)" ::: "memory");
    __builtin_amdgcn_s_barrier();
  }

  __bf16* pk = (EPI == 4) ? ((kc == 0) ? P0 : (kc == 1) ? P1 : (kc == 2) ? P2 : P3)
                          : nullptr;
#pragma unroll
  for (int f = 0; f < 8; f++) {
    int row0 = m0 + (f >> 2) * 128 + (f & 3) * 32 + wm * 16 + g * 4;
#pragma unroll
    for (int ni = 0; ni < 4; ni++) {
      int col = n0 + (ni >> 1) * 128 + (ni & 1) * 64 + wn * 16 + lo;
      if (EPI == 0) {
        int sE = col >> 10, rem = col & 1023, hh = rem >> 6, dd = rem & 63;
        if (sE < 2) {
          float qs = (sE == 0) ? 0.1803368801111204f : 1.0f;  // 0.125*log2(e)
#pragma unroll
          for (int r = 0; r < 4; r++)
            outb[((size_t)(sE * 16 + hh) * 4096 + row0 + r) * 64 + dd] =
                (__bf16)(acc[f][ni][r] * qs);
        } else {
          bf16x4 pk4;
#pragma unroll
          for (int r = 0; r < 4; r++) pk4[r] = (__bf16)acc[f][ni][r];
          *(bf16x4*)&outb[(size_t)32 * 4096 * 64 + ((size_t)(hh * 64 + dd)) * 4096 + row0] = pk4;
        }
      } else if (EPI == 2) {
        float bv = bias[col];
#pragma unroll
        for (int r = 0; r < 4; r++) {
          float vv = acc[f][ni][r] + bv;
          float gg = 0.5f * vv * (1.0f + erff(vv * 0.70710678118f));
          outb[(size_t)(row0 + r) * N + col] = (__bf16)gg;
        }
      } else {
#pragma unroll
        for (int r = 0; r < 4; r++)
          pk[(size_t)(row0 + r) * N + col] = (__bf16)acc[f][ni][r];
      }
    }
  }
}

// ---------------- split-K reduce: out = x2 + p0+p1+p2+p3 + bias  (4096x1024)
__global__ __launch_bounds__(256) void ff2_reduce_kernel(
    const __bf16* __restrict__ p0, const __bf16* __restrict__ p1,
    const __bf16* __restrict__ p2, const __bf16* __restrict__ p3,
    const float* __restrict__ x2, const float* __restrict__ bias,
    float* __restrict__ out) {
  size_t i8 = ((size_t)blockIdx.x * 256 + threadIdx.x) * 8;
  bf16x8 a = *(const bf16x8*)&p0[i8];
  bf16x8 b = *(const bf16x8*)&p1[i8];
  bf16x8 c = *(const bf16x8*)&p2[i8];
  bf16x8 d = *(const bf16x8*)&p3[i8];
  int col = (int)(i8 & 1023);
  float4 xa = *(const float4*)&x2[i8];
  float4 xb = *(const float4*)&x2[i8 + 4];
  float4 ba = *(const float4*)&bias[col];
  float4 bb = *(const float4*)&bias[col + 4];
  float4 oa, ob;
  oa.x = xa.x + ba.x + (float)a[0] + (float)b[0] + (float)c[0] + (float)d[0];
  oa.y = xa.y + ba.y + (float)a[1] + (float)b[1] + (float)c[1] + (float)d[1];
  oa.z = xa.z + ba.z + (float)a[2] + (float)b[2] + (float)c[2] + (float)d[2];
  oa.w = xa.w + ba.w + (float)a[3] + (float)b[3] + (float)c[3] + (float)d[3];
  ob.x = xb.x + bb.x + (float)a[4] + (float)b[4] + (float)c[4] + (float)d[4];
  ob.y = xb.y + bb.y + (float)a[5] + (float)b[5] + (float)c[5] + (float)d[5];
  ob.z = xb.z + bb.z + (float)a[6] + (float)b[6] + (float)c[6] + (float)d[6];
  ob.w = xb.w + bb.w + (float)a[7] + (float)b[7] + (float)c[7] + (float)d[7];
  *(float4*)&out[i8] = oa;
  *(float4*)&out[i8 + 4] = ob;
}

// ---------------- causal flash attention (bid < 512) + piggybacked weight
// transposes (bid >= 512). Block = 512 thr = 8 waves = (qsub 0-3) x (kpar 0-1).
// SINGLE-BUFFERED 32 KiB LDS ([par][K/V]) at launch_bounds(512,4) (VGPR 64,
// no spill) -> 4 blocks/CU = 32 waves/CU; stage latency hidden across blocks.
// kpar merge via R11 scheme: unnormalized bf16 partials in 17 KiB bounce.
// Q pre-scaled by 0.125*log2e, static-max softmax, l via ones-MFMA.
__global__ __launch_bounds__(512, 4) void attn_fused_kernel(
    const __bf16* __restrict__ Q, const __bf16* __restrict__ Kb,
    const __bf16* __restrict__ VTb, __bf16* __restrict__ O,
    const float* __restrict__ w_o, __bf16* __restrict__ woT,
    const float* __restrict__ w_ff1, __bf16* __restrict__ wff1T,
    const float* __restrict__ w_ff2, __bf16* __restrict__ wff2T) {
  constexpr int NSEQ = 4096;
  __shared__ __bf16 lds[2][2][64 * 64];  // [par][K/VT], 32 KiB
  int orig = blockIdx.x;
  int t = threadIdx.x;

  if (orig >= 512) {
    // ---- transpose body: in [K][N] f32 -> out [N][K] bf16, 512 threads
    int b = orig - 512;
    const float* in; __bf16* outw; int K, N, bx, by;
    if (b < 1024)      { in = w_o;   outw = woT;   K = 1024; N = 1024; bx = b & 31;  by = b >> 5; }
    else if (b < 5120) { int c = b - 1024; in = w_ff1; outw = wff1T; K = 1024; N = 4096; bx = c & 127; by = c >> 7; }
    else               { int c = b - 5120; in = w_ff2; outw = wff2T; K = 4096; N = 1024; bx = c & 31;  by = c >> 5; }
    float* tile = (float*)lds;  // [32][33]
    int tx = t & 31, ty = t >> 5;  // ty 0..15
#pragma unroll
    for (int j = 0; j < 2; j++) {
      int r = ty + j * 16;
      tile[r * 33 + tx] = in[(size_t)(by * 32 + r) * N + bx * 32 + tx];
    }
    __syncthreads();
#pragma unroll
    for (int j = 0; j < 2; j++) {
      int r = ty + j * 16;
      outw[(size_t)(bx * 32 + r) * K + by * 32 + tx] = (__bf16)tile[tx * 33 + r];
    }
    return;
  }

  int xcd = orig & 7, rank = orig >> 3;  // rank 0..63
  int hv = rank >> 5;
  int hd2 = (rank >> 4) & 1;
  int itr = rank & 15;
  int head = xcd * 2 + hd2;
  int it = hv ? itr : (31 - itr);        // complementary pairs sum to 31
  int wid = t >> 6, lane = t & 63;
  int lo = lane & 31, hi = lane >> 5;
  int qsub = wid & 3, kpar = wid >> 2;
  const __bf16* kh = Kb + (size_t)head * NSEQ * 64;
  const __bf16* vth = VTb + (size_t)head * 64 * NSEQ;
  int qlow = it * 128 + qsub * 32;
  int qrow = qlow + lo;
  int qtop = qlow + 31;
  const __bf16* qh = Q + (size_t)head * NSEQ * 64 + (size_t)qrow * 64;
  bf16x8 bq[4];
#pragma unroll
  for (int c = 0; c < 4; c++) bq[c] = *(const bf16x8*)(qh + c * 16 + hi * 8);

  const unsigned onesu = 0x3F803F80u;  // 2 x bf16 1.0
  uint4v onev = {onesu, onesu, onesu, onesu};
  bf16x8 vones = __builtin_bit_cast(bf16x8, onev);

  f32x16 acc0 = {}, acc1 = {};
  f32x16 lacc = {};              // row-sum accumulator via ones-MFMA
  int srow = t >> 3;             // 0..63
  int sgs = ((t & 7) ^ (srow & 7)) * 8;

  int off[4];
#pragma unroll
  for (int c = 0; c < 4; c++) off[c] = lo * 64 + (((c * 2 + hi) ^ (lo & 7)) * 8);
  const __bf16* lk = &lds[kpar][0][0];
  const __bf16* lvt = &lds[kpar][1][0];
  const __bf16* khs = kh + srow * 64 + sgs;
  const __bf16* vts = vth + (size_t)srow * NSEQ + sgs;

  // stage both parity tiles for step j: K/V tiles 2j (par0) and 2j+1 (par1)
  auto stage_pair = [&](int j) {
    gload_lds16(khs + (size_t)(2 * j) * 4096, &lds[0][0][t * 8]);
    gload_lds16(vts + (2 * j) * 64, &lds[0][1][t * 8]);
    gload_lds16(khs + (size_t)(2 * j + 1) * 4096, &lds[1][0][t * 8]);
    gload_lds16(vts + (2 * j + 1) * 64, &lds[1][1][t * 8]);
  };

  int ns = it + 1;
  for (int j = 0; j < ns; j++) {
    stage_pair(j);
    __syncthreads();  // drains vmcnt; tiles visible
    int kt = 2 * j + kpar;
    if (kt * 64 <= qtop) {
      f32x16 s0 = {}, s1 = {};
      __builtin_amdgcn_s_setprio(1);
#pragma unroll
      for (int c = 0; c < 4; c++) {
        bf16x8 ka0 = *(const bf16x8*)&lk[off[c]];
        bf16x8 ka1 = *(const bf16x8*)&lk[2048 + off[c]];
        s0 = MFMA32(ka0, bq[c], s0);
        s1 = MFMA32(ka1, bq[c], s1);
      }
      __builtin_amdgcn_s_setprio(0);
      if (kt * 64 + 63 > qlow) {
#pragma unroll
        for (int i = 0; i < 16; i++) {
          int key0 = kt * 64 + (i & 3) + 8 * (i >> 2) + 4 * hi;
          if (key0 > qrow) s0[i] = -3.0e38f;
          if (key0 + 32 > qrow) s1[i] = -3.0e38f;
        }
      }
#pragma unroll
      for (int i = 0; i < 16; i++) {
        s0[i] = fexp2(s0[i]);
        s1[i] = fexp2(s1[i]);
      }
      uint4v pw[4];
#pragma unroll
      for (int b = 0; b < 2; b++) {
        int off2 = b * 8;
        unsigned a0 = pkbf(s0[off2 + 0], s0[off2 + 1]);
        unsigned a1 = pkbf(s0[off2 + 2], s0[off2 + 3]);
        unsigned b0 = pkbf(s0[off2 + 4], s0[off2 + 5]);
        unsigned b1 = pkbf(s0[off2 + 6], s0[off2 + 7]);
        asm("v_permlane32_swap_b32 %0, %1" : "+v"(a0), "+v"(b0));
        asm("v_permlane32_swap_b32 %0, %1" : "+v"(a1), "+v"(b1));
        pw[b][0] = a0; pw[b][1] = a1; pw[b][2] = b0; pw[b][3] = b1;
        unsigned c0 = pkbf(s1[off2 + 0], s1[off2 + 1]);
        unsigned c1 = pkbf(s1[off2 + 2], s1[off2 + 3]);
        unsigned d0 = pkbf(s1[off2 + 4], s1[off2 + 5]);
        unsigned d1 = pkbf(s1[off2 + 6], s1[off2 + 7]);
        asm("v_permlane32_swap_b32 %0, %1" : "+v"(c0), "+v"(d0));
        asm("v_permlane32_swap_b32 %0, %1" : "+v"(c1), "+v"(d1));
        pw[2 + b][0] = c0; pw[2 + b][1] = c1; pw[2 + b][2] = d0;
        pw[2 + b][3] = d1;
      }
      __builtin_amdgcn_s_setprio(1);
#pragma unroll
      for (int b = 0; b < 4; b++) {
        bf16x8 pf = __builtin_bit_cast(bf16x8, pw[b]);
        bf16x8 va0 = *(const bf16x8*)&lvt[off[b]];
        bf16x8 va1 = *(const bf16x8*)&lvt[2048 + off[b]];
        acc0 = MFMA32(va0, pf, acc0);
        acc1 = MFMA32(va1, pf, acc1);
        lacc = MFMA32(vones, pf, lacc);
      }
      __builtin_amdgcn_s_setprio(0);
    }
    __syncthreads();  // all reads done before next overwrite
  }

  // ---- merge (R11 scheme, 17 KiB): kpar=1 writes UNNORMALIZED bf16 partials
  // (swizzled bounce) + l; kpar=0 adds own acc, normalizes, writes back, stores.
  float* fl = (float*)lds;
  float* lbuf = fl;                        // [4][64] f32 = 1 KiB
  __bf16* bounce = (__bf16*)(fl + 256);    // 4 x 2048 bf16 = 16 KiB
  __bf16* region = bounce + qsub * 2048;
  if (kpar == 1) {
    lbuf[qsub * 64 + lane] = lacc[0];
#pragma unroll
    for (int dt = 0; dt < 2; dt++) {
#pragma unroll
      for (int rp = 0; rp < 8; rp++) {
        int rr = rp * 2;
        float e0 = dt ? acc1[rr] : acc0[rr];
        float e1 = dt ? acc1[rr + 1] : acc0[rr + 1];
        int d = dt * 32 + (rr & 3) + 8 * (rr >> 2) + 4 * hi;
        int bytecol = d * 2;
        int g16 = bytecol >> 4, rem16 = bytecol & 15;
        *(unsigned*)((char*)region + lo * 128 + ((g16 ^ (lo & 7)) * 16 + rem16)) = pkbf(e0, e1);
      }
    }
  }
  __syncthreads();
  if (kpar == 0) {
    float linv = 1.0f / (lacc[0] + lbuf[qsub * 64 + lane]);
#pragma unroll
    for (int dt = 0; dt < 2; dt++) {
#pragma unroll
      for (int rp = 0; rp < 8; rp++) {
        int rr = rp * 2;
        int d = dt * 32 + (rr & 3) + 8 * (rr >> 2) + 4 * hi;
        int bytecol = d * 2;
        int g16 = bytecol >> 4, rem16 = bytecol & 15;
        unsigned* addr = (unsigned*)((char*)region + lo * 128 + ((g16 ^ (lo & 7)) * 16 + rem16));
        unsigned u = *addr;
        float plo = (float)__builtin_bit_cast(__bf16, (unsigned short)(u & 0xffff));
        float phi = (float)__builtin_bit_cast(__bf16, (unsigned short)(u >> 16));
        float e0 = ((dt ? acc1[rr] : acc0[rr]) + plo) * linv;
        float e1 = ((dt ? acc1[rr + 1] : acc0[rr + 1]) + phi) * linv;
        *addr = pkbf(e0, e1);
      }
    }
#pragma unroll
    for (int j2 = 0; j2 < 4; j2++) {
      int idx = j2 * 64 + lane;
      int row = idx >> 3, g = idx & 7;
      bf16x8 v = *(const bf16x8*)((char*)region + row * 128 + ((g ^ (row & 7)) * 16));
      *(bf16x8*)&O[(size_t)(it * 128 + qsub * 32 + row) * 1024 + head * 64 + g * 8] = v;
    }
  }
}

extern "C" void kernel_launch(void* const* d_in, const int* in_sizes, int n_in,
                              void* d_out, int out_size, void* d_ws, size_t ws_size,
                              hipStream_t stream) {
  const float* x = (const float*)d_in[0];
  const float* ln1_w = (const float*)d_in[1];
  const float* ln1_b = (const float*)d_in[2];
  const float* ln2_w = (const float*)d_in[3];
  const float* ln2_b = (const float*)d_in[4];
  const float* w_qkv = (const float*)d_in[5];  // [1024][3072]
  const float* w_o = (const float*)d_in[6];    // [1024][1024]
  const float* w_ff1 = (const float*)d_in[7];  // [1024][4096]
  const float* b_ff1 = (const float*)d_in[8];
  const float* w_ff2 = (const float*)d_in[9];  // [4096][1024]
  const float* b_ff2 = (const float*)d_in[10];
  float* out = (float*)d_out;

  const size_t D = 1024, NT = 4096;
  __bf16* wqkvT = (__bf16*)d_ws;                 // [0,6) MB
  __bf16* woT = wqkvT + 3072 * D;                // [6,8)
  __bf16* wff1T = woT + D * D;                   // [8,16)
  __bf16* wff2T = wff1T + 4096 * D;              // [16,24)
  __bf16* hbuf = wff2T + D * 4096;               // [24,32)
  __bf16* qkvb = hbuf + NT * D;                  // [32,56)
  __bf16* attnb = qkvb + 3 * NT * D;             // [56,64)
  __bf16* a1 = qkvb;                             // [32,64) overlaps dead qkv
  float* x2 = (float*)(attnb + NT * D);          // [64,80) f32
  __bf16* p0 = (__bf16*)d_ws;                    // [0,8)  (wqkvT/woT dead by ff2)
  __bf16* p1 = p0 + NT * D;                      // [8,16) (wff1T dead after ff1)
  __bf16* p2 = hbuf;                             // [24,32) (h2 dead after ff1)
  __bf16* p3 = (__bf16*)(x2 + NT * D);           // [80,88)
  __bf16* pA = qkvb;                             // [32,40) dead q after attn-out
  __bf16* pB = pA + NT * D;                      // [40,48) dead k after attn-out

  dim3 tb(32, 8);
  pre_kernel<<<3072 + 4096, tb, 0, stream>>>(w_qkv, wqkvT, x, ln1_w, ln1_b, hbuf);
  gemm256_kernel<0><<<192, 512, 0, stream>>>(hbuf, wqkvT, 4096, 3072, 1024, 16,
                                             nullptr, qkvb, nullptr, nullptr, nullptr, nullptr);
  // attention (512 blocks x 8 waves, single-buffered 32 KiB) + transposes
  attn_fused_kernel<<<512 + 9216, 512, 0, stream>>>(
      qkvb, qkvb + 16 * NT * 64, qkvb + 32 * NT * 64, attnb,
      w_o, woT, w_ff1, wff1T, w_ff2, wff2T);
  gemm_splitk128_kernel<<<dim3(8, 32, 2), 256, 0, stream>>>(
      attnb, woT, 4096, 1024, 1024, 512, pA);
  out_reduce_ln_kernel<<<4096, 256, 0, stream>>>(pA, pB, x, ln2_w, ln2_b, x2, hbuf);
  gemm256_kernel<2><<<256, 512, 0, stream>>>(hbuf, wff1T, 4096, 4096, 1024, 16,
                                             b_ff1, a1, nullptr, nullptr, nullptr, nullptr);
  gemm256_kernel<4><<<dim3(64, 4), 512, 0, stream>>>(a1, wff2T, 4096, 1024, 4096, 16,
                                                     nullptr, nullptr, p0, p1, p2, p3);
  ff2_reduce_kernel<<<2048, 256, 0, stream>>>(p0, p1, p2, p3, x2, b_ff2, out);
}

// Round 19
// 228.114 us; speedup vs baseline: 1.0550x; 1.0176x over previous
//
#include <hip/hip_runtime.h>
#include <hip/hip_bf16.h>
#include <cstdint>
#include <cstddef>

typedef __attribute__((ext_vector_type(8))) __bf16 bf16x8;
typedef __attribute__((ext_vector_type(4))) __bf16 bf16x4;
typedef __attribute__((ext_vector_type(4))) float f32x4;
typedef __attribute__((ext_vector_type(16))) float f32x16;
typedef __attribute__((ext_vector_type(4))) unsigned int uint4v;

#define MFMA16(a, b, c) __builtin_amdgcn_mfma_f32_16x16x32_bf16(a, b, c, 0, 0, 0)
#define MFMA32(a, b, c) __builtin_amdgcn_mfma_f32_32x32x16_bf16(a, b, c, 0, 0, 0)

__device__ __forceinline__ void gload_lds16(const void* g, void* l) {
  __builtin_amdgcn_global_load_lds(
      (__attribute__((address_space(1))) uint32_t*)g,
      (__attribute__((address_space(3))) uint32_t*)l,
      16, 0, 0);
}

__device__ __forceinline__ unsigned pkbf(float a, float b) {
  unsigned short x = __builtin_bit_cast(unsigned short, (__bf16)a);
  unsigned short y = __builtin_bit_cast(unsigned short, (__bf16)b);
  return (unsigned)x | ((unsigned)y << 16);
}

__device__ __forceinline__ float fexp2(float x) {
  float r;
  asm("v_exp_f32 %0, %1" : "=v"(r) : "v"(x));
  return r;
}

// ---------------- pre: qkv weight transpose (bid<3072) + LN1 (bid>=3072)
__global__ __launch_bounds__(256) void pre_kernel(
    const float* __restrict__ w_qkv, __bf16* __restrict__ wqkvT,
    const float* __restrict__ x, const float* __restrict__ ln1_w,
    const float* __restrict__ ln1_b, __bf16* __restrict__ h) {
  __shared__ float sm[32 * 33];
  int bid = blockIdx.x;
  int tx = threadIdx.x, ty = threadIdx.y;  // (32, 8)
  if (bid < 3072) {
    int bx = bid % 96, by = bid / 96;  // N=3072, K=1024
    int gcol = bx * 32 + tx;
#pragma unroll
    for (int j = 0; j < 4; j++) {
      int grow = by * 32 + ty + j * 8;
      sm[(ty + j * 8) * 33 + tx] = w_qkv[(size_t)grow * 3072 + gcol];
    }
    __syncthreads();
#pragma unroll
    for (int j = 0; j < 4; j++) {
      int n = bx * 32 + ty + j * 8;
      wqkvT[(size_t)n * 1024 + by * 32 + tx] = (__bf16)sm[tx * 33 + ty + j * 8];
    }
    return;
  }
  int row = bid - 3072;
  int t = ty * 32 + tx;
  const float4* xr = (const float4*)(x + (size_t)row * 1024);
  float4 v = xr[t];
  float s = v.x + v.y + v.z + v.w;
  float sq = v.x * v.x + v.y * v.y + v.z * v.z + v.w * v.w;
#pragma unroll
  for (int m = 1; m < 64; m <<= 1) {
    s += __shfl_xor(s, m);
    sq += __shfl_xor(sq, m);
  }
  float* rs = sm;
  float* rq = sm + 4;
  int wid = t >> 6;
  if ((t & 63) == 0) { rs[wid] = s; rq[wid] = sq; }
  __syncthreads();
  s = rs[0] + rs[1] + rs[2] + rs[3];
  sq = rq[0] + rq[1] + rq[2] + rq[3];
  float mean = s * (1.0f / 1024.0f);
  float var = sq * (1.0f / 1024.0f) - mean * mean;
  float rstd = rsqrtf(var + 1e-5f);
  float4 wv = ((const float4*)ln1_w)[t];
  float4 bv = ((const float4*)ln1_b)[t];
  bf16x4 o;
  o[0] = (__bf16)((v.x - mean) * rstd * wv.x + bv.x);
  o[1] = (__bf16)((v.y - mean) * rstd * wv.y + bv.y);
  o[2] = (__bf16)((v.z - mean) * rstd * wv.z + bv.z);
  o[3] = (__bf16)((v.w - mean) * rstd * wv.w + bv.w);
  *(bf16x4*)(h + (size_t)row * 1024 + t * 4) = o;
}

// ---------------- 128^2-tile split-K GEMM (m97 structure): bf16 partials
__global__ __launch_bounds__(256, 2) void gemm_splitk128_kernel(
    const __bf16* __restrict__ A, const __bf16* __restrict__ BT,
    int M, int N, int K, int kchunk, __bf16* __restrict__ P) {
  __shared__ __bf16 lsA[128 * 64];
  __shared__ __bf16 lsB[128 * 64];
  int t = threadIdx.x;
  int m0 = blockIdx.y * 128, n0 = blockIdx.x * 128;
  int kbase = blockIdx.z * kchunk;
  __bf16* pout = P + (size_t)blockIdx.z * M * N;
  int wid = t >> 6, lane = t & 63, lo = lane & 15, g = lane >> 4;
  int wr = wid >> 1, wc = wid & 1;
  f32x4 acc[4][4] = {};
  const __bf16* ag = A + (size_t)(m0 + (t >> 3)) * K + (t & 7) * 8;
  const __bf16* bg = BT + (size_t)(n0 + (t >> 3)) * K + (t & 7) * 8;
  for (int k0 = kbase; k0 < kbase + kchunk; k0 += 64) {
#pragma unroll
    for (int i = 0; i < 4; i++) {
      gload_lds16(ag + (size_t)i * 32 * K + k0, &lsA[i * 2048 + t * 8]);
      gload_lds16(bg + (size_t)i * 32 * K + k0, &lsB[i * 2048 + t * 8]);
    }
    __syncthreads();
#pragma unroll
    for (int kk = 0; kk < 2; kk++) {
      bf16x8 af[4], bfr[4];
#pragma unroll
      for (int mi = 0; mi < 4; mi++)
        af[mi] = *(const bf16x8*)&lsA[(wr * 64 + mi * 16 + lo) * 64 + kk * 32 + g * 8];
#pragma unroll
      for (int ni = 0; ni < 4; ni++)
        bfr[ni] = *(const bf16x8*)&lsB[(wc * 64 + ni * 16 + lo) * 64 + kk * 32 + g * 8];
#pragma unroll
      for (int mi = 0; mi < 4; mi++)
#pragma unroll
        for (int ni = 0; ni < 4; ni++)
          acc[mi][ni] = MFMA16(af[mi], bfr[ni], acc[mi][ni]);
    }
    __syncthreads();
  }
#pragma unroll
  for (int mi = 0; mi < 4; mi++) {
#pragma unroll
    for (int ni = 0; ni < 4; ni++) {
      int col = n0 + wc * 64 + ni * 16 + lo;
      int row0 = m0 + wr * 64 + mi * 16 + g * 4;
#pragma unroll
      for (int r = 0; r < 4; r++)
        pout[(size_t)(row0 + r) * N + col] = (__bf16)acc[mi][ni][r];
    }
  }
}

// ---------------- fused reduce + LN2: x2 = x + p0 + p1; h = LN(x2).  One block/row.
__global__ __launch_bounds__(256) void out_reduce_ln_kernel(
    const __bf16* __restrict__ p0, const __bf16* __restrict__ p1,
    const float* __restrict__ x, const float* __restrict__ w,
    const float* __restrict__ b, float* __restrict__ x2,
    __bf16* __restrict__ h) {
  int row = blockIdx.x, t = threadIdx.x;
  size_t base = (size_t)row * 1024 + t * 4;
  bf16x4 a = *(const bf16x4*)&p0[base];
  bf16x4 b4 = *(const bf16x4*)&p1[base];
  float4 xv = *(const float4*)&x[base];
  float4 v;
  v.x = xv.x + (float)a[0] + (float)b4[0];
  v.y = xv.y + (float)a[1] + (float)b4[1];
  v.z = xv.z + (float)a[2] + (float)b4[2];
  v.w = xv.w + (float)a[3] + (float)b4[3];
  *(float4*)&x2[base] = v;
  float s = v.x + v.y + v.z + v.w;
  float sq = v.x * v.x + v.y * v.y + v.z * v.z + v.w * v.w;
#pragma unroll
  for (int m = 1; m < 64; m <<= 1) {
    s += __shfl_xor(s, m);
    sq += __shfl_xor(sq, m);
  }
  __shared__ float rs[4], rq[4];
  int wid = t >> 6;
  if ((t & 63) == 0) { rs[wid] = s; rq[wid] = sq; }
  __syncthreads();
  s = rs[0] + rs[1] + rs[2] + rs[3];
  sq = rq[0] + rq[1] + rq[2] + rq[3];
  float mean = s * (1.0f / 1024.0f);
  float var = sq * (1.0f / 1024.0f) - mean * mean;
  float rstd = rsqrtf(var + 1e-5f);
  float4 wv = ((const float4*)w)[t];
  float4 bv = ((const float4*)b)[t];
  bf16x4 o;
  o[0] = (__bf16)((v.x - mean) * rstd * wv.x + bv.x);
  o[1] = (__bf16)((v.y - mean) * rstd * wv.y + bv.y);
  o[2] = (__bf16)((v.z - mean) * rstd * wv.z + bv.z);
  o[3] = (__bf16)((v.w - mean) * rstd * wv.w + bv.w);
  *(bf16x4*)&h[base] = o;
}

// ---------------- 256^2-tile 8-phase GEMM (T2+T3+T4+T5)
// EPI 0: scatter q (PRE-SCALED by 0.125*log2e), k to [2][16][4096][64],
//        v TRANSPOSED to [16][64][4096]
// EPI 2: outb = gelu(acc + bias) bf16
// EPI 4: split-K partial -> bf16 buffer P[kchunk] (blockIdx.y = kchunk)
template <int EPI>
__global__ __launch_bounds__(512, 2) void gemm256_kernel(
    const __bf16* __restrict__ A, const __bf16* __restrict__ BT,
    int M, int N, int K, int nkc,
    const float* __restrict__ bias, __bf16* __restrict__ outb,
    __bf16* __restrict__ P0, __bf16* __restrict__ P1,
    __bf16* __restrict__ P2, __bf16* __restrict__ P3) {
  __shared__ __bf16 lsA[2][2][128 * 64];
  __shared__ __bf16 lsB[2][2][128 * 64];
  int nbx = N >> 8;
  int nwg = (M >> 8) * nbx;
  int bid = blockIdx.x;
  int swz = (bid & 7) * (nwg >> 3) + (bid >> 3);
  int m0 = (swz / nbx) << 8, n0 = (swz % nbx) << 8;
  int kc = blockIdx.y;
  int kt0 = kc * nkc;
  int t = threadIdx.x;
  int wid = t >> 6, lane = t & 63, lo = lane & 15, g = lane >> 4;
  int wm = wid >> 2, wn = wid & 3;
  int srow = t >> 3, sgrp = t & 7;

  auto stA = [&](int d, int h, int kt) {
#pragma unroll
    for (int i = 0; i < 2; i++) {
      int row = i * 64 + srow;
      int gs = (sgrp ^ (row & 7)) * 8;
      gload_lds16(A + (size_t)(m0 + h * 128 + row) * K + kt * 64 + gs,
                  &lsA[d][h][(i * 512 + t) * 8]);
    }
  };
  auto stB = [&](int d, int h, int kt) {
#pragma unroll
    for (int i = 0; i < 2; i++) {
      int row = i * 64 + srow;
      int gs = (sgrp ^ (row & 7)) * 8;
      gload_lds16(BT + (size_t)(n0 + h * 128 + row) * K + kt * 64 + gs,
                  &lsB[d][h][(i * 512 + t) * 8]);
    }
  };
  auto rdA = [&](int d, int f, int kk) -> bf16x8 {
    int row = (f & 3) * 32 + wm * 16 + lo;
    return *(const bf16x8*)&lsA[d][f >> 2][row * 64 + (((kk * 4 + g) ^ (lo & 7)) * 8)];
  };
  auto rdB = [&](int d, int ni, int kk) -> bf16x8 {
    int row = (ni & 1) * 64 + wn * 16 + lo;
    return *(const bf16x8*)&lsB[d][ni >> 1][row * 64 + (((kk * 4 + g) ^ (lo & 7)) * 8)];
  };

  f32x4 acc[8][4] = {};
  stA(0, 0, kt0); stB(0, 0, kt0); stB(0, 1, kt0); stA(0, 1, kt0);
  asm volatile("s_waitcnt vmcnt(4)" ::: "memory");
  __builtin_amdgcn_s_barrier();

  for (int ki = 0; ki < nkc; ki++) {
    int kt = kt0 + ki;
    int d = ki & 1, nx = d ^ 1;
    bool pf = (ki + 1) < nkc;
    bf16x8 fa[4][2], fb0[2][2], fb1[2][2];
#pragma unroll
    for (int f = 0; f < 4; f++) { fa[f][0] = rdA(d, f, 0); fa[f][1] = rdA(d, f, 1); }
#pragma unroll
    for (int n = 0; n < 2; n++) { fb0[n][0] = rdB(d, n, 0); fb0[n][1] = rdB(d, n, 1); }
    if (pf) { stA(nx, 0, kt + 1); stB(nx, 0, kt + 1); }
    __builtin_amdgcn_s_barrier();
    __builtin_amdgcn_s_setprio(1);
#pragma unroll
    for (int f = 0; f < 4; f++)
#pragma unroll
      for (int n = 0; n < 2; n++) {
        acc[f][n] = MFMA16(fa[f][0], fb0[n][0], acc[f][n]);
        acc[f][n] = MFMA16(fa[f][1], fb0[n][1], acc[f][n]);
      }
    __builtin_amdgcn_s_setprio(0);
    asm volatile("s_waitcnt vmcnt(6)" ::: "memory");
    __builtin_amdgcn_s_barrier();
#pragma unroll
    for (int n = 0; n < 2; n++) { fb1[n][0] = rdB(d, 2 + n, 0); fb1[n][1] = rdB(d, 2 + n, 1); }
    if (pf) stB(nx, 1, kt + 1);
    __builtin_amdgcn_s_barrier();
    __builtin_amdgcn_s_setprio(1);
#pragma unroll
    for (int f = 0; f < 4; f++)
#pragma unroll
      for (int n = 0; n < 2; n++) {
        acc[f][2 + n] = MFMA16(fa[f][0], fb1[n][0], acc[f][2 + n]);
        acc[f][2 + n] = MFMA16(fa[f][1], fb1[n][1], acc[f][2 + n]);
      }
    __builtin_amdgcn_s_setprio(0);
    asm volatile("s_waitcnt vmcnt(6)" ::: "memory");
    __builtin_amdgcn_s_barrier();
#pragma unroll
    for (int f = 0; f < 4; f++) { fa[f][0] = rdA(d, 4 + f, 0); fa[f][1] = rdA(d, 4 + f, 1); }
    if (pf) stA(nx, 1, kt + 1);
    __builtin_amdgcn_s_barrier();
    __builtin_amdgcn_s_setprio(1);
#pragma unroll
    for (int f = 0; f < 4; f++)
#pragma unroll
      for (int n = 0; n < 2; n++) {
        acc[4 + f][2 + n] = MFMA16(fa[f][0], fb1[n][0], acc[4 + f][2 + n]);
        acc[4 + f][2 + n] = MFMA16(fa[f][1], fb1[n][1], acc[4 + f][2 + n]);
      }
    __builtin_amdgcn_s_setprio(0);
    __builtin_amdgcn_s_barrier();
    __builtin_amdgcn_s_setprio(1);
#pragma unroll
    for (int f = 0; f < 4; f++)
#pragma unroll
      for (int n = 0; n < 2; n++) {
        acc[4 + f][n] = MFMA16(fa[f][0], fb0[n][0], acc[4 + f][n]);
        acc[4 + f][n] = MFMA16(fa[f][1], fb0[n][1], acc[4 + f][n]);
      }
    __builtin_amdgcn_s_setprio(0);
    asm volatile("s_waitcnt vmcnt(4)" ::: "memory");
    __builtin_amdgcn_s_barrier();
  }

  __bf16* pk = (EPI == 4) ? ((kc == 0) ? P0 : (kc == 1) ? P1 : (kc == 2) ? P2 : P3)
                          : nullptr;
#pragma unroll
  for (int f = 0; f < 8; f++) {
    int row0 = m0 + (f >> 2) * 128 + (f & 3) * 32 + wm * 16 + g * 4;
#pragma unroll
    for (int ni = 0; ni < 4; ni++) {
      int col = n0 + (ni >> 1) * 128 + (ni & 1) * 64 + wn * 16 + lo;
      if (EPI == 0) {
        int sE = col >> 10, rem = col & 1023, hh = rem >> 6, dd = rem & 63;
        if (sE < 2) {
          float qs = (sE == 0) ? 0.1803368801111204f : 1.0f;  // 0.125*log2(e)
#pragma unroll
          for (int r = 0; r < 4; r++)
            outb[((size_t)(sE * 16 + hh) * 4096 + row0 + r) * 64 + dd] =
                (__bf16)(acc[f][ni][r] * qs);
        } else {
          bf16x4 pk4;
#pragma unroll
          for (int r = 0; r < 4; r++) pk4[r] = (__bf16)acc[f][ni][r];
          *(bf16x4*)&outb[(size_t)32 * 4096 * 64 + ((size_t)(hh * 64 + dd)) * 4096 + row0] = pk4;
        }
      } else if (EPI == 2) {
        float bv = bias[col];
#pragma unroll
        for (int r = 0; r < 4; r++) {
          float vv = acc[f][ni][r] + bv;
          float gg = 0.5f * vv * (1.0f + erff(vv * 0.70710678118f));
          outb[(size_t)(row0 + r) * N + col] = (__bf16)gg;
        }
      } else {
#pragma unroll
        for (int r = 0; r < 4; r++)
          pk[(size_t)(row0 + r) * N + col] = (__bf16)acc[f][ni][r];
      }
    }
  }
}

// ---------------- split-K reduce: out = x2 + p0+p1+p2+p3 + bias  (4096x1024)
__global__ __launch_bounds__(256) void ff2_reduce_kernel(
    const __bf16* __restrict__ p0, const __bf16* __restrict__ p1,
    const __bf16* __restrict__ p2, const __bf16* __restrict__ p3,
    const float* __restrict__ x2, const float* __restrict__ bias,
    float* __restrict__ out) {
  size_t i8 = ((size_t)blockIdx.x * 256 + threadIdx.x) * 8;
  bf16x8 a = *(const bf16x8*)&p0[i8];
  bf16x8 b = *(const bf16x8*)&p1[i8];
  bf16x8 c = *(const bf16x8*)&p2[i8];
  bf16x8 d = *(const bf16x8*)&p3[i8];
  int col = (int)(i8 & 1023);
  float4 xa = *(const float4*)&x2[i8];
  float4 xb = *(const float4*)&x2[i8 + 4];
  float4 ba = *(const float4*)&bias[col];
  float4 bb = *(const float4*)&bias[col + 4];
  float4 oa, ob;
  oa.x = xa.x + ba.x + (float)a[0] + (float)b[0] + (float)c[0] + (float)d[0];
  oa.y = xa.y + ba.y + (float)a[1] + (float)b[1] + (float)c[1] + (float)d[1];
  oa.z = xa.z + ba.z + (float)a[2] + (float)b[2] + (float)c[2] + (float)d[2];
  oa.w = xa.w + ba.w + (float)a[3] + (float)b[3] + (float)c[3] + (float)d[3];
  ob.x = xb.x + bb.x + (float)a[4] + (float)b[4] + (float)c[4] + (float)d[4];
  ob.y = xb.y + bb.y + (float)a[5] + (float)b[5] + (float)c[5] + (float)d[5];
  ob.z = xb.z + bb.z + (float)a[6] + (float)b[6] + (float)c[6] + (float)d[6];
  ob.w = xb.w + bb.w + (float)a[7] + (float)b[7] + (float)c[7] + (float)d[7];
  *(float4*)&out[i8] = oa;
  *(float4*)&out[i8 + 4] = ob;
}

// ---------------- causal flash attention (bid < 512) + piggybacked weight
// transposes for w_o/w_ff1/w_ff2 (bid >= 512, backfill attn's tail).
// Attn: swapped-QK^T 32x32, 128-row q-tiles, 8 waves = (qsub 0-3) x (kpar 0-1),
// Q pre-scaled by 0.125*log2e, static-max softmax, l via ones-MFMA.
__global__ __launch_bounds__(512, 4) void attn_fused_kernel(
    const __bf16* __restrict__ Q, const __bf16* __restrict__ Kb,
    const __bf16* __restrict__ VTb, __bf16* __restrict__ O,
    const float* __restrict__ w_o, __bf16* __restrict__ woT,
    const float* __restrict__ w_ff1, __bf16* __restrict__ wff1T,
    const float* __restrict__ w_ff2, __bf16* __restrict__ wff2T) {
  constexpr int NSEQ = 4096;
  __shared__ __bf16 lds[2][2][2][64 * 64];  // attn: [dbl][par][K/VT]; transpose: tile
  int orig = blockIdx.x;
  int t = threadIdx.x;

  if (orig >= 512) {
    // ---- transpose body: in [K][N] f32 -> out [N][K] bf16, 512 threads
    int b = orig - 512;
    const float* in; __bf16* outw; int K, N, bx, by;
    if (b < 1024)      { in = w_o;   outw = woT;   K = 1024; N = 1024; bx = b & 31;  by = b >> 5; }
    else if (b < 5120) { int c = b - 1024; in = w_ff1; outw = wff1T; K = 1024; N = 4096; bx = c & 127; by = c >> 7; }
    else               { int c = b - 5120; in = w_ff2; outw = wff2T; K = 4096; N = 1024; bx = c & 31;  by = c >> 5; }
    float* tile = (float*)lds;  // [32][33]
    int tx = t & 31, ty = t >> 5;  // ty 0..15
#pragma unroll
    for (int j = 0; j < 2; j++) {
      int r = ty + j * 16;
      tile[r * 33 + tx] = in[(size_t)(by * 32 + r) * N + bx * 32 + tx];
    }
    __syncthreads();
#pragma unroll
    for (int j = 0; j < 2; j++) {
      int r = ty + j * 16;
      outw[(size_t)(bx * 32 + r) * K + by * 32 + tx] = (__bf16)tile[tx * 33 + r];
    }
    return;
  }

  int xcd = orig & 7, rank = orig >> 3;  // rank 0..63
  int hv = rank >> 5;
  int hd2 = (rank >> 4) & 1;
  int itr = rank & 15;
  int head = xcd * 2 + hd2;
  int it = hv ? itr : (31 - itr);        // complementary pairs sum to 31
  int wid = t >> 6, lane = t & 63;
  int lo = lane & 31, hi = lane >> 5;
  int qsub = wid & 3, kpar = wid >> 2;
  const __bf16* kh = Kb + (size_t)head * NSEQ * 64;
  const __bf16* vth = VTb + (size_t)head * 64 * NSEQ;
  int qlow = it * 128 + qsub * 32;
  int qrow = qlow + lo;
  const __bf16* qh = Q + (size_t)head * NSEQ * 64 + (size_t)qrow * 64;
  bf16x8 bq[4];
#pragma unroll
  for (int c = 0; c < 4; c++) bq[c] = *(const bf16x8*)(qh + c * 16 + hi * 8);

  const unsigned onesu = 0x3F803F80u;  // 2 x bf16 1.0
  uint4v onev = {onesu, onesu, onesu, onesu};
  bf16x8 vones = __builtin_bit_cast(bf16x8, onev);

  f32x16 acc0 = {}, acc1 = {};
  f32x16 lacc = {};              // row-sum accumulator via ones-MFMA
  int srow = t >> 3;
  int sgs = ((t & 7) ^ (srow & 7)) * 8;

  int off[4];
#pragma unroll
  for (int c = 0; c < 4; c++) off[c] = lo * 64 + (((c * 2 + hi) ^ (lo & 7)) * 8);
  const __bf16* lk0 = &lds[0][kpar][0][0];
  const __bf16* lk1 = &lds[1][kpar][0][0];
  const __bf16* lv0 = &lds[0][kpar][1][0];
  const __bf16* lv1 = &lds[1][kpar][1][0];
  const __bf16* khs = kh + srow * 64 + sgs;
  const __bf16* vts = vth + (size_t)srow * NSEQ + sgs;

  auto stage_tile = [&](int d, int par, int kt) {
    gload_lds16(khs + (size_t)kt * 4096, &lds[d][par][0][t * 8]);
    gload_lds16(vts + kt * 64, &lds[d][par][1][t * 8]);
  };

  int ns = it + 1;
  int qtop = qlow + 31;
  stage_tile(0, 0, 0);
  stage_tile(0, 1, 1);
  __syncthreads();

#define ATTN_STEP(CUR)                                                         \
  {                                                                            \
    if (j + 1 < ns) {                                                          \
      stage_tile((CUR) ^ 1, 0, 2 * j + 2);                                     \
      stage_tile((CUR) ^ 1, 1, 2 * j + 3);                                     \
    }                                                                          \
    int kt = 2 * j + kpar;                                                     \
    if (kt * 64 <= qtop) {                                                     \
      const __bf16* lk = (CUR) ? lk1 : lk0;                                    \
      const __bf16* lvt = (CUR) ? lv1 : lv0;                                   \
      f32x16 s0 = {}, s1 = {};                                                 \
      __builtin_amdgcn_s_setprio(1);                                           \
      _Pragma("unroll") for (int c = 0; c < 4; c++) {                          \
        bf16x8 ka0 = *(const bf16x8*)&lk[off[c]];                              \
        bf16x8 ka1 = *(const bf16x8*)&lk[2048 + off[c]];                       \
        s0 = MFMA32(ka0, bq[c], s0);                                           \
        s1 = MFMA32(ka1, bq[c], s1);                                           \
      }                                                                        \
      __builtin_amdgcn_s_setprio(0);                                           \
      if (kt * 64 + 63 > qlow) {                                               \
        _Pragma("unroll") for (int i = 0; i < 16; i++) {                       \
          int key0 = kt * 64 + (i & 3) + 8 * (i >> 2) + 4 * hi;                \
          if (key0 > qrow) s0[i] = -3.0e38f;                                   \
          if (key0 + 32 > qrow) s1[i] = -3.0e38f;                              \
        }                                                                      \
      }                                                                        \
      _Pragma("unroll") for (int i = 0; i < 16; i++) {                         \
        s0[i] = fexp2(s0[i]);                                                  \
        s1[i] = fexp2(s1[i]);                                                  \
      }                                                                        \
      uint4v pw[4];                                                            \
      _Pragma("unroll") for (int b = 0; b < 2; b++) {                          \
        int off2 = b * 8;                                                      \
        unsigned a0 = pkbf(s0[off2 + 0], s0[off2 + 1]);                        \
        unsigned a1 = pkbf(s0[off2 + 2], s0[off2 + 3]);                        \
        unsigned b0 = pkbf(s0[off2 + 4], s0[off2 + 5]);                        \
        unsigned b1 = pkbf(s0[off2 + 6], s0[off2 + 7]);                        \
        asm("v_permlane32_swap_b32 %0, %1" : "+v"(a0), "+v"(b0));              \
        asm("v_permlane32_swap_b32 %0, %1" : "+v"(a1), "+v"(b1));              \
        pw[b][0] = a0; pw[b][1] = a1; pw[b][2] = b0; pw[b][3] = b1;            \
        unsigned c0 = pkbf(s1[off2 + 0], s1[off2 + 1]);                        \
        unsigned c1 = pkbf(s1[off2 + 2], s1[off2 + 3]);                        \
        unsigned d0 = pkbf(s1[off2 + 4], s1[off2 + 5]);                        \
        unsigned d1 = pkbf(s1[off2 + 6], s1[off2 + 7]);                        \
        asm("v_permlane32_swap_b32 %0, %1" : "+v"(c0), "+v"(d0));              \
        asm("v_permlane32_swap_b32 %0, %1" : "+v"(c1), "+v"(d1));              \
        pw[2 + b][0] = c0; pw[2 + b][1] = c1; pw[2 + b][2] = d0;               \
        pw[2 + b][3] = d1;                                                     \
      }                                                                        \
      __builtin_amdgcn_s_setprio(1);                                           \
      _Pragma("unroll") for (int b = 0; b < 4; b++) {                          \
        bf16x8 pf = __builtin_bit_cast(bf16x8, pw[b]);                         \
        bf16x8 va0 = *(const bf16x8*)&lvt[off[b]];                             \
        bf16x8 va1 = *(const bf16x8*)&lvt[2048 + off[b]];                      \
        acc0 = MFMA32(va0, pf, acc0);                                          \
        acc1 = MFMA32(va1, pf, acc1);                                          \
        lacc = MFMA32(vones, pf, lacc);                                        \
      }                                                                        \
      __builtin_amdgcn_s_setprio(0);                                           \
    }                                                                          \
    __syncthreads();                                                           \
  }

  int j = 0;
  for (;;) {
    ATTN_STEP(0);
    if (++j >= ns) break;
    ATTN_STEP(1);
    if (++j >= ns) break;
  }
#undef ATTN_STEP

  float* fl = (float*)lds;
  float* lbuf = fl;                          // [4][64]
  float* ab = fl + 256;                      // [(qsub*64+lane)*36 + 0..31]
  __bf16* bounce = (__bf16*)(fl + 256 + 9216);
  if (kpar == 1) {
    lbuf[qsub * 64 + lane] = lacc[0];
    int base = (qsub * 64 + lane) * 36;
#pragma unroll
    for (int k2 = 0; k2 < 16; k2 += 4) {
      float4 v0; v0.x = acc0[k2]; v0.y = acc0[k2 + 1]; v0.z = acc0[k2 + 2]; v0.w = acc0[k2 + 3];
      *(float4*)&ab[base + k2] = v0;
      float4 v1; v1.x = acc1[k2]; v1.y = acc1[k2 + 1]; v1.z = acc1[k2 + 2]; v1.w = acc1[k2 + 3];
      *(float4*)&ab[base + 16 + k2] = v1;
    }
  }
  __syncthreads();
  if (kpar == 0) {
    float lsum = lacc[0] + lbuf[qsub * 64 + lane];
    float linv = 1.0f / lsum;
    int base = (qsub * 64 + lane) * 36;
    f32x16 b0, b1;
#pragma unroll
    for (int k2 = 0; k2 < 16; k2 += 4) {
      float4 v0 = *(float4*)&ab[base + k2];
      b0[k2] = v0.x; b0[k2 + 1] = v0.y; b0[k2 + 2] = v0.z; b0[k2 + 3] = v0.w;
      float4 v1 = *(float4*)&ab[base + 16 + k2];
      b1[k2] = v1.x; b1[k2 + 1] = v1.y; b1[k2 + 2] = v1.z; b1[k2 + 3] = v1.w;
    }
    __bf16* region = bounce + qsub * 2048;
#pragma unroll
    for (int dt = 0; dt < 2; dt++) {
#pragma unroll
      for (int rp = 0; rp < 8; rp++) {
        int r = rp * 2;
        float a0 = dt ? acc1[r] : acc0[r], a1 = dt ? acc1[r + 1] : acc0[r + 1];
        float c0 = dt ? b1[r] : b0[r], c1 = dt ? b1[r + 1] : b0[r + 1];
        float e0 = (a0 + c0) * linv;
        float e1 = (a1 + c1) * linv;
        int d = dt * 32 + (r & 3) + 8 * (r >> 2) + 4 * hi;
        int bytecol = d * 2;
        int g16 = bytecol >> 4, rem16 = bytecol & 15;
        *(unsigned*)((char*)region + lo * 128 + ((g16 ^ (lo & 7)) * 16 + rem16)) = pkbf(e0, e1);
      }
    }
#pragma unroll
    for (int j2 = 0; j2 < 4; j2++) {
      int idx = j2 * 64 + lane;
      int row = idx >> 3, g = idx & 7;
      bf16x8 v = *(const bf16x8*)((char*)region + row * 128 + ((g ^ (row & 7)) * 16));
      *(bf16x8*)&O[(size_t)(it * 128 + qsub * 32 + row) * 1024 + head * 64 + g * 8] = v;
    }
  }
}

extern "C" void kernel_launch(void* const* d_in, const int* in_sizes, int n_in,
                              void* d_out, int out_size, void* d_ws, size_t ws_size,
                              hipStream_t stream) {
  const float* x = (const float*)d_in[0];
  const float* ln1_w = (const float*)d_in[1];
  const float* ln1_b = (const float*)d_in[2];
  const float* ln2_w = (const float*)d_in[3];
  const float* ln2_b = (const float*)d_in[4];
  const float* w_qkv = (const float*)d_in[5];  // [1024][3072]
  const float* w_o = (const float*)d_in[6];    // [1024][1024]
  const float* w_ff1 = (const float*)d_in[7];  // [1024][4096]
  const float* b_ff1 = (const float*)d_in[8];
  const float* w_ff2 = (const float*)d_in[9];  // [4096][1024]
  const float* b_ff2 = (const float*)d_in[10];
  float* out = (float*)d_out;

  const size_t D = 1024, NT = 4096;
  __bf16* wqkvT = (__bf16*)d_ws;                 // [0,6) MB
  __bf16* woT = wqkvT + 3072 * D;                // [6,8)
  __bf16* wff1T = woT + D * D;                   // [8,16)
  __bf16* wff2T = wff1T + 4096 * D;              // [16,24)
  __bf16* hbuf = wff2T + D * 4096;               // [24,32)
  __bf16* qkvb = hbuf + NT * D;                  // [32,56)
  __bf16* attnb = qkvb + 3 * NT * D;             // [56,64)
  __bf16* a1 = qkvb;                             // [32,64) overlaps dead qkv+attn
  float* x2 = (float*)(attnb + NT * D);          // [64,80) f32
  __bf16* p0 = (__bf16*)d_ws;                    // [0,8)  (wqkvT/woT dead by ff2)
  __bf16* p1 = p0 + NT * D;                      // [8,16) (wff1T dead after ff1)
  __bf16* p2 = hbuf;                             // [24,32) (h2 dead after ff1)
  __bf16* p3 = (__bf16*)(x2 + NT * D);           // [80,88)
  __bf16* pA = qkvb;                             // [32,40) dead q after attn
  __bf16* pB = pA + NT * D;                      // [40,48) dead k after attn

  dim3 tb(32, 8);
  // qkv transpose + LN1 merged
  pre_kernel<<<3072 + 4096, tb, 0, stream>>>(w_qkv, wqkvT, x, ln1_w, ln1_b, hbuf);
  // qkv = h @ w_qkv (256^2 8-phase), scatter to q/k/vT
  gemm256_kernel<0><<<192, 512, 0, stream>>>(hbuf, wqkvT, 4096, 3072, 1024, 16,
                                             nullptr, qkvb, nullptr, nullptr, nullptr, nullptr);
  // attention + piggybacked wo/ff1/ff2 transposes (9216 extra blocks)
  attn_fused_kernel<<<512 + 9216, 512, 0, stream>>>(
      qkvb, qkvb + 16 * NT * 64, qkvb + 32 * NT * 64, attnb,
      w_o, woT, w_ff1, wff1T, w_ff2, wff2T);
  gemm_splitk128_kernel<<<dim3(8, 32, 2), 256, 0, stream>>>(
      attnb, woT, 4096, 1024, 1024, 512, pA);
  out_reduce_ln_kernel<<<4096, 256, 0, stream>>>(pA, pB, x, ln2_w, ln2_b, x2, hbuf);
  gemm256_kernel<2><<<256, 512, 0, stream>>>(hbuf, wff1T, 4096, 4096, 1024, 16,
                                             b_ff1, a1, nullptr, nullptr, nullptr, nullptr);
  gemm256_kernel<4><<<dim3(64, 4), 512, 0, stream>>>(a1, wff2T, 4096, 1024, 4096, 16,
                                                     nullptr, nullptr, p0, p1, p2, p3);
  ff2_reduce_kernel<<<2048, 256, 0, stream>>>(p0, p1, p2, p3, x2, b_ff2, out);
}